// Round 4
// baseline (1704.352 us; speedup 1.0000x reference)
//
#include <hip/hip_runtime.h>
#include <hip/hip_bf16.h>

typedef __attribute__((ext_vector_type(8))) short short8;
typedef __attribute__((ext_vector_type(4))) short short4v;
typedef __attribute__((ext_vector_type(4))) float floatx4;
typedef __hip_bfloat16 bf16;

#define M1 1048576L  // 1024*1024

__device__ __forceinline__ void async16(const short* g, short* l) {
  __builtin_amdgcn_global_load_lds((const __attribute__((address_space(1))) void*)g,
                                   (__attribute__((address_space(3))) void*)l, 16, 0, 0);
}

// ------------------------------------------------------- shared GEMM core ---
// 128x128 tile, bf16 MFMA 16x16x32, B transposed ([N][ldb], K-contiguous).
__device__ __forceinline__ void gemm_loop(const short* A, const short* B, int K,
    int lda, int ldb, short* sA, short* sB, int m0, int n0, floatx4 (&acc)[4][4]) {
  const int tid = threadIdx.x, wave = tid >> 6, lane = tid & 63;
  const int lane15 = lane & 15, quad = lane >> 4;
  const int mW = (wave & 1) * 64, nW = (wave >> 1) * 64;
  const int ldrow = lane >> 2, kcol = (lane & 3) * 8;
#pragma unroll
  for (int i = 0; i < 4; i++)
#pragma unroll
    for (int j = 0; j < 4; j++) { floatx4 zz = {0.f, 0.f, 0.f, 0.f}; acc[i][j] = zz; }
  for (int k0 = 0; k0 < K; k0 += 32) {
    __syncthreads();
#pragma unroll
    for (int it = 0; it < 2; it++) {
      const int ca = wave * 2 + it;
      async16(A + (long)(m0 + ca * 16 + ldrow) * lda + k0 + kcol, sA + ca * 512);
      async16(B + (long)(n0 + ca * 16 + ldrow) * ldb + k0 + kcol, sB + ca * 512);
    }
    __syncthreads();
    short8 af[4], bfr[4];
#pragma unroll
    for (int mt = 0; mt < 4; mt++)
      af[mt] = *(const short8*)(sA + (mW + mt * 16 + lane15) * 32 + quad * 8);
#pragma unroll
    for (int nt = 0; nt < 4; nt++)
      bfr[nt] = *(const short8*)(sB + (nW + nt * 16 + lane15) * 32 + quad * 8);
#pragma unroll
    for (int mt = 0; mt < 4; mt++)
#pragma unroll
      for (int nt = 0; nt < 4; nt++)
        acc[mt][nt] = __builtin_amdgcn_mfma_f32_16x16x32_bf16(af[mt], bfr[nt], acc[mt][nt], 0, 0, 0);
  }
}

// flags: 1=C^T  2=f32  8=atomicAdd accumulate (f32 C^T)  16=bias only on z2==0
__device__ __forceinline__ void gemm_epi(void* C, const float* bias, long cOff,
    int ldc, int fl, int m0, int n0, floatx4 (&acc)[4][4]) {
  const int lane = threadIdx.x & 63, wave = threadIdx.x >> 6;
  const int lane15 = lane & 15, quad = lane >> 4;
  const int mW = (wave & 1) * 64, nW = (wave >> 1) * 64;
#pragma unroll
  for (int mt = 0; mt < 4; mt++)
#pragma unroll
    for (int nt = 0; nt < 4; nt++) {
      const int mg = m0 + mW + mt * 16 + quad * 4;
      const int ng = n0 + nW + nt * 16 + lane15;
      floatx4 v = acc[mt][nt];
      if (bias) {
        v.x += bias[mg + 0]; v.y += bias[mg + 1];
        v.z += bias[mg + 2]; v.w += bias[mg + 3];
      }
      if (fl & 1) {  // C^T: [N][ldc]
        const long o = cOff + (long)ng * ldc + mg;
        if (fl & 8) {
          float* cp = (float*)C + o;
          atomicAdd(cp + 0, v.x); atomicAdd(cp + 1, v.y);
          atomicAdd(cp + 2, v.z); atomicAdd(cp + 3, v.w);
        } else if (fl & 2) {
          float* cp = (float*)C + o;
          cp[0] = v.x; cp[1] = v.y; cp[2] = v.z; cp[3] = v.w;
        } else {
          bf16* cp = (bf16*)C + o;
          cp[0] = __float2bfloat16(v.x); cp[1] = __float2bfloat16(v.y);
          cp[2] = __float2bfloat16(v.z); cp[3] = __float2bfloat16(v.w);
        }
      } else {       // plain C: [M][ldc]
        const long o = cOff + (long)mg * ldc + ng;
        if (fl & 2) {
          float* cp = (float*)C + o;
          cp[0] = v.x; cp[ldc] = v.y; cp[2L * ldc] = v.z; cp[3L * ldc] = v.w;
        } else {
          bf16* cp = (bf16*)C + o;
          cp[0] = __float2bfloat16(v.x); cp[ldc] = __float2bfloat16(v.y);
          cp[2L * ldc] = __float2bfloat16(v.z); cp[3L * ldc] = __float2bfloat16(v.w);
        }
      }
    }
}

// ------------------------------------------------- generic strided-z GEMM ---
struct GemmP {
  const short* A; const short* B; void* C; const float* bias;
  long sA1, sA2, sB1, sB2, sC1, sC2, sb1, sb2;
  int M, N, K, lda, ldb, ldc, Z2, flags;
};

__global__ __launch_bounds__(256) void gemm_kernel(GemmP p) {
  __shared__ __align__(16) short sA[4096];
  __shared__ __align__(16) short sB[4096];
  const int z = blockIdx.z, z1 = z / p.Z2, z2 = z % p.Z2;
  const short* A = p.A + z1 * p.sA1 + z2 * p.sA2;
  const short* B = p.B + z1 * p.sB1 + z2 * p.sB2;
  const long cOff = z1 * p.sC1 + z2 * p.sC2;
  const float* bias = p.bias;
  if (bias) {
    if ((p.flags & 16) && z2 != 0) bias = 0;
    else bias += z1 * p.sb1 + z2 * p.sb2;
  }
  floatx4 acc[4][4];
  gemm_loop(A, B, p.K, p.lda, p.ldb, sA, sB, blockIdx.y * 128, blockIdx.x * 128, acc);
  gemm_epi(p.C, bias, cOff, p.ldc, p.flags, blockIdx.y * 128, blockIdx.x * 128, acc);
}

// ------------------------------------- 3-way batched GEMM (proj / QKV) ------
// z = w*4 + b; w selects {W,F,C,bias,flags,K,ld}; b = batch.
// B = F[w] + b*1024*K[w]; C offset = b*M1 (elements of C's dtype).
struct QkvP {
  const short* W[3]; const short* F[3]; void* C[3]; const float* bias[3];
  int fl[3], Kd[3], ld[3];
};

__global__ __launch_bounds__(256) void qkv_kernel(QkvP q) {
  __shared__ __align__(16) short sA[4096];
  __shared__ __align__(16) short sB[4096];
  const int z = blockIdx.z, w = z >> 2, b = z & 3;
  const int K = q.Kd[w], ld = q.ld[w];
  const short* A = q.W[w];
  const short* B = q.F[w] + (long)b * 1024 * K;
  floatx4 acc[4][4];
  gemm_loop(A, B, K, ld, ld, sA, sB, blockIdx.y * 128, blockIdx.x * 128, acc);
  gemm_epi(q.C[w], q.bias[w], (long)b * M1, 1024, q.fl[w], blockIdx.y * 128, blockIdx.x * 128, acc);
}

// --------------------------- fused scores + softmax (one block per (b,h)) ---
// Q,Kt: [4][1024 c][1024 d] bf16; P: [32][128][128] bf16 row-major.
__global__ __launch_bounds__(256) void attn_sm_k(const short* Q, const short* Kt, bf16* P) {
  __shared__ __align__(16) short sA[4096];
  __shared__ __align__(16) short sB[4096];
  __shared__ short S16[128 * 132];
  const int z = blockIdx.x, b = z >> 3, h = z & 7;
  const short* A = Q + (long)b * M1 + (long)h * 131072;
  const short* B = Kt + (long)b * M1 + (long)h * 131072;
  floatx4 acc[4][4];
  gemm_loop(A, B, 1024, 1024, 1024, sA, sB, 0, 0, acc);
  const int lane = threadIdx.x & 63, wave = threadIdx.x >> 6;
  const int lane15 = lane & 15, quad = lane >> 4;
  const int mW = (wave & 1) * 64, nW = (wave >> 1) * 64;
  const float sc = 0.08838834764831845f;   // 128^-0.5
#pragma unroll
  for (int mt = 0; mt < 4; mt++)
#pragma unroll
    for (int nt = 0; nt < 4; nt++) {
      const int mg = mW + mt * 16 + quad * 4, ng = nW + nt * 16 + lane15;
      floatx4 v = acc[mt][nt];
      *(bf16*)&S16[(mg + 0) * 132 + ng] = __float2bfloat16(v.x * sc);
      *(bf16*)&S16[(mg + 1) * 132 + ng] = __float2bfloat16(v.y * sc);
      *(bf16*)&S16[(mg + 2) * 132 + ng] = __float2bfloat16(v.z * sc);
      *(bf16*)&S16[(mg + 3) * 132 + ng] = __float2bfloat16(v.w * sc);
    }
  __syncthreads();
  bf16* Pb = P + (long)z * 16384;
  for (int r = wave * 32; r < wave * 32 + 32; r++) {
    float a = __bfloat162float(*(bf16*)&S16[r * 132 + lane]);
    float c = __bfloat162float(*(bf16*)&S16[r * 132 + lane + 64]);
    float m = fmaxf(a, c);
    for (int off = 32; off; off >>= 1) m = fmaxf(m, __shfl_xor(m, off));
    float e0 = expf(a - m), e1 = expf(c - m), s = e0 + e1;
    for (int off = 32; off; off >>= 1) s += __shfl_xor(s, off);
    const float inv = 1.0f / s;
    Pb[r * 128 + lane] = __float2bfloat16(e0 * inv);
    Pb[r * 128 + lane + 64] = __float2bfloat16(e1 * inv);
  }
}

// -------------------------------------------------------- f32 -> bf16 -------
__global__ void cvt_k(const float* src, bf16* dst, long n) {
  long i = ((long)blockIdx.x * 256 + threadIdx.x) * 4;
  if (i + 3 < n) {
    float4 v = *(const float4*)(src + i);
    bf16 t[4] = {__float2bfloat16(v.x), __float2bfloat16(v.y),
                 __float2bfloat16(v.z), __float2bfloat16(v.w)};
    *(short4v*)(dst + i) = *(short4v*)t;
  }
}

struct Cvt4 { const float* s[4]; bf16* d[4]; long n[4]; };
__global__ void cvt4_k(Cvt4 c) {
  const int seg = blockIdx.y;
  long i = ((long)blockIdx.x * 256 + threadIdx.x) * 4;
  if (i + 3 < c.n[seg]) {
    float4 v = *(const float4*)(c.s[seg] + i);
    bf16 t[4] = {__float2bfloat16(v.x), __float2bfloat16(v.y),
                 __float2bfloat16(v.z), __float2bfloat16(v.w)};
    *(short4v*)(c.d[seg] + i) = *(short4v*)t;
  }
}

// ------------------------------------------------------------ transpose -----
// in [B][C][D] f32 -> out [B][D][C] bf16
__global__ void trans_k(const float* in, bf16* out, int C, int D) {
  __shared__ float tile[32][33];
  const int d0 = blockIdx.x * 32, c0 = blockIdx.y * 32, b = blockIdx.z;
  const float* ib = in + (long)b * C * D;
  bf16* ob = out + (long)b * C * D;
  for (int i = threadIdx.y; i < 32; i += 8)
    tile[i][threadIdx.x] = ib[(long)(c0 + i) * D + d0 + threadIdx.x];
  __syncthreads();
  for (int i = threadIdx.y; i < 32; i += 8)
    ob[(long)(d0 + i) * C + c0 + threadIdx.x] = __float2bfloat16(tile[threadIdx.x][i]);
}

// ------------------------------------------------------ l2norm + metrics ----
__global__ __launch_bounds__(256) void norm_k(float* cross, bf16* feat, float* metrics) {
  const int blk = blockIdx.x;     // mod*4096 + pix
  const int mod = blk >> 12;
  float* base = cross + (long)blk * 1024;
  bf16* fb = feat + (long)blk * 1024;
  const int t = threadIdx.x;
  float v[4]; float ssq = 0.f;
#pragma unroll
  for (int j = 0; j < 4; j++) { v[j] = base[t + j * 256]; ssq += v[j] * v[j]; }
  __shared__ float r1[256], r2[256], r3[256];
  __shared__ float sinv;
  r1[t] = ssq; __syncthreads();
  for (int s = 128; s > 0; s >>= 1) { if (t < s) r1[t] += r1[t + s]; __syncthreads(); }
  if (t == 0) sinv = 1.0f / fmaxf(sqrtf(r1[0]), 1e-12f);
  __syncthreads();
  const float invn = sinv;
  float s1 = 0.f, s2 = 0.f, zc = 0.f;
#pragma unroll
  for (int j = 0; j < 4; j++) {
    float x = v[j] * invn; v[j] = x;
    s1 += x; s2 += x * x; if (x == 0.0f) zc += 1.0f;
  }
  r1[t] = s1; r2[t] = s2; r3[t] = zc; __syncthreads();
  for (int s = 128; s > 0; s >>= 1) {
    if (t < s) { r1[t] += r1[t + s]; r2[t] += r2[t + s]; r3[t] += r3[t + s]; }
    __syncthreads();
  }
  if (t == 0) {
    float m = (mod == 0) ? (r2[0] - r1[0] * r1[0] * (1.0f / 1024.f)) * (1.0f / 1023.f)
                         : r3[0] * (1.0f / 1024.f);
    metrics[blk] = m;
  }
#pragma unroll
  for (int j = 0; j < 4; j++) { base[t + j * 256] = v[j]; fb[t + j * 256] = __float2bfloat16(v[j]); }
}

// ----------------------------------------------------------------- SE -------
__global__ void zero_k(float* p, int n) {
  int i = blockIdx.x * 256 + threadIdx.x;
  if (i < n) p[i] = 0.f;
}

__global__ void pool_k(const float* cross, float* pooled) {
  const int blk = blockIdx.x;          // mb*16 + seg, mb = mod*4+b
  const int seg = blk & 15, mb = blk >> 4;
  const float* base = cross + (long)mb * M1 + (long)seg * 64 * 1024;
  float* pout = pooled + (long)mb * 1024;
  for (int c = threadIdx.x; c < 1024; c += 256) {
    float s = 0.f;
    for (int d = 0; d < 64; d++) s += base[(long)d * 1024 + c];
    atomicAdd(&pout[c], s * (1.0f / 1024.0f));
  }
}

__global__ void se_k(const float* pooled, const float* w1, const float* b1,
                     const float* w2, const float* b2, float* gvec) {
  const int mb = blockIdx.x, mod = mb >> 2, t = threadIdx.x;
  __shared__ float ps[1024]; __shared__ float hs[64];
  const float* p = pooled + (long)mb * 1024;
  for (int c = t; c < 1024; c += 256) ps[c] = p[c];
  __syncthreads();
  if (t < 64) {
    const float* wr = w1 + (long)(mod * 64 + t) * 1024;
    float s = 0.f;
    for (int c = 0; c < 1024; c++) s += wr[c] * ps[c];
    s += b1[mod * 64 + t];
    hs[t] = fmaxf(s, 0.f);
  }
  __syncthreads();
  for (int o = t; o < 1024; o += 256) {
    const float* wr = w2 + (long)(mod * 1024 + o) * 64;
    float s = 0.f;
    for (int j = 0; j < 64; j++) s += wr[j] * hs[j];
    s += b2[mod * 1024 + o];
    gvec[(long)mb * 1024 + o] = 1.0f / (1.0f + expf(-s));
  }
}

// ------------------------------------------------------- gates + fused ------
__global__ __launch_bounds__(256) void gatefuse_k(const float* cross, const float* gvec,
    const float* metrics, const float* gw, const float* gb, bf16* fused) {
  const int pix = blockIdx.x;          // b*1024 + d
  const int b = pix >> 10, t = threadIdx.x;
  __shared__ float refbuf[3072];
  __shared__ float red[3][256];
  __shared__ float gsh[3];
  float p0 = 0.f, p1 = 0.f, p2 = 0.f;
  for (int mod = 0; mod < 3; mod++) {
    const float* cb = cross + ((long)mod * 4096 + pix) * 1024;
    const float* gv = gvec + (long)(mod * 4 + b) * 1024;
    for (int c = t; c < 1024; c += 256) {
      float val = cb[c] * gv[c];
      refbuf[mod * 1024 + c] = val;
      p0 += gw[0 * 3075 + mod * 1024 + c] * val;
      p1 += gw[1 * 3075 + mod * 1024 + c] * val;
      p2 += gw[2 * 3075 + mod * 1024 + c] * val;
    }
  }
  red[0][t] = p0; red[1][t] = p1; red[2][t] = p2; __syncthreads();
  for (int s = 128; s > 0; s >>= 1) {
    if (t < s) { red[0][t] += red[0][t + s]; red[1][t] += red[1][t + s]; red[2][t] += red[2][t + s]; }
    __syncthreads();
  }
  if (t == 0) {
    const float var = metrics[pix], spd = metrics[4096 + pix], spl = metrics[8192 + pix];
    for (int j = 0; j < 3; j++) {
      float s = red[j][0] + gw[j * 3075 + 3072] * var + gw[j * 3075 + 3073] * spd
              + gw[j * 3075 + 3074] * spl + gb[j];
      gsh[j] = 1.0f / (1.0f + expf(-s));
    }
  }
  __syncthreads();
  bf16* fb = fused + (long)pix * 3072;
  for (int i = t; i < 3072; i += 256) fb[i] = __float2bfloat16(refbuf[i] * gsh[i >> 10]);
}

// ---------------------------------------------------------------- host ------
extern "C" void kernel_launch(void* const* d_in, const int* in_sizes, int n_in,
                              void* d_out, int out_size, void* d_ws, size_t ws_size,
                              hipStream_t stream) {
  const float* rgb = (const float*)d_in[0];
  const float* dep = (const float*)d_in[1];
  const float* lid = (const float*)d_in[2];
  const float* pw[3] = {(const float*)d_in[3], (const float*)d_in[5], (const float*)d_in[7]};
  const float* pb[3] = {(const float*)d_in[4], (const float*)d_in[6], (const float*)d_in[8]};
  const float* qw = (const float*)d_in[9];  const float* qb = (const float*)d_in[10];
  const float* kw = (const float*)d_in[11]; const float* kb = (const float*)d_in[12];
  const float* vw = (const float*)d_in[13]; const float* vb = (const float*)d_in[14];
  const float* ow = (const float*)d_in[15]; const float* obv = (const float*)d_in[16];
  const float* sew1 = (const float*)d_in[17]; const float* seb1 = (const float*)d_in[18];
  const float* sew2 = (const float*)d_in[19]; const float* seb2 = (const float*)d_in[20];
  const float* gw = (const float*)d_in[21];   const float* gb = (const float*)d_in[22];
  const float* fw = (const float*)d_in[23]; const float* fbias = (const float*)d_in[24];

  // ---- workspace: ~107 MB peak (lifetime-aliased; proven safe) ----
  char* wp = (char*)d_ws;
  auto carve = [&](size_t bytes) -> char* {
    char* r = wp; wp += (bytes + 255) & ~(size_t)255; return r;
  };
  float* cross = (float*)carve(12L * M1 * 4);    // [3][4][1024 d][1024 c] f32, persists
  short* feat  = (short*)carve(12L * M1 * 2);    // bf16 normalized feats; dead after attn -> fwb
  char*  S     = carve(35L * 1024 * 1024);       // shared scratch region
  float* metrics = (float*)carve(3L * 4096 * 4);
  float* pooled  = (float*)carve(12L * 1024 * 4);
  float* gvec    = (float*)carve(12L * 1024 * 4);

  // S phase 1 (dead after projections):
  short* rgbT = (short*)S;                          // 4 MB  [4][1024 d][512 c]
  short* depT = (short*)(S + 4L  * 1024 * 1024);    // 2 MB
  short* lidT = (short*)(S + 6L  * 1024 * 1024);    // 0.5 MB
  short* pwb[3] = {(short*)(S + 8L * 1024 * 1024),
                   (short*)(S + 9L * 1024 * 1024),
                   (short*)(S + 9728L * 1024)};
  // S phase 2 (per attention block i):
  short* Qi  = (short*)S;                           // 8 MB [4][1024 c][1024 d]
  short* Ki  = (short*)(S + 8L  * 1024 * 1024);     // 8 MB
  short* Vi  = (short*)(S + 16L * 1024 * 1024);     // 8 MB [4][1024 d][1024 c]
  short* OAi = (short*)(S + 24L * 1024 * 1024);     // 8 MB (weights wq/wk/wv live here pre-PV)
  short* wqb = (short*)(S + 24L * 1024 * 1024);     // 2 MB
  short* wkb = (short*)(S + 26L * 1024 * 1024);     // 2 MB
  short* wvb = (short*)(S + 28L * 1024 * 1024);     // 2 MB
  short* wob = (short*)(S + 32L * 1024 * 1024);     // 2 MB (survives PV)
  short* P   = (short*)(S + 34L * 1024 * 1024);     // 1 MB bf16 [32][128][128]
  // S phase 3:
  short* fused = (short*)S;                         // 24 MB [4][1024 d][3072 c]
  short* fwb   = feat;                              // 18 MB (feat slot)

  auto G = [&](dim3 grid, GemmP g) { gemm_kernel<<<grid, dim3(256), 0, stream>>>(g); };

  // 1) transpose+convert raw inputs [B,C,D] f32 -> [B,D,C] bf16
  trans_k<<<dim3(32, 16, 4), dim3(32, 8), 0, stream>>>(rgb, (bf16*)rgbT, 512, 1024);
  trans_k<<<dim3(32, 8, 4),  dim3(32, 8), 0, stream>>>(dep, (bf16*)depT, 256, 1024);
  trans_k<<<dim3(32, 2, 4),  dim3(32, 8), 0, stream>>>(lid, (bf16*)lidT, 64, 1024);

  // 2) proj weights -> bf16 (one 3-segment launch), then merged proj GEMM (z=12)
  {
    Cvt4 c{};
    c.s[0] = pw[0]; c.d[0] = (bf16*)pwb[0]; c.n[0] = 1024L * 512;
    c.s[1] = pw[1]; c.d[1] = (bf16*)pwb[1]; c.n[1] = 1024L * 256;
    c.s[2] = pw[2]; c.d[2] = (bf16*)pwb[2]; c.n[2] = 1024L * 64;
    c.s[3] = pw[2]; c.d[3] = (bf16*)pwb[2]; c.n[3] = 0;
    cvt4_k<<<dim3(512, 4), dim3(256), 0, stream>>>(c);

    QkvP q{};
    const int Ks[3] = {512, 256, 64};
    const short* Bts[3] = {rgbT, depT, lidT};
    for (int m = 0; m < 3; m++) {
      q.W[m] = pwb[m]; q.F[m] = Bts[m]; q.C[m] = cross + (long)m * 4 * M1;
      q.bias[m] = pb[m]; q.fl[m] = 1 | 2; q.Kd[m] = Ks[m]; q.ld[m] = Ks[m];
    }
    qkv_kernel<<<dim3(8, 8, 12), dim3(256), 0, stream>>>(q);
  }

  // 3) l2norm (in-place) + bf16 feat copy + quality metrics
  norm_k<<<dim3(12288), dim3(256), 0, stream>>>(cross, (bf16*)feat, metrics);

  // 4) attention blocks one at a time
  {
    const int qm[6] = {0, 0, 1, 1, 2, 2};
    const int km[6] = {1, 2, 0, 2, 0, 1};
    for (int i = 0; i < 6; i++) {
      // convert Wq,Wk,Wv,Wo for this block in one launch
      Cvt4 c{};
      c.s[0] = qw + (long)i * M1; c.d[0] = (bf16*)wqb; c.n[0] = M1;
      c.s[1] = kw + (long)i * M1; c.d[1] = (bf16*)wkb; c.n[1] = M1;
      c.s[2] = vw + (long)i * M1; c.d[2] = (bf16*)wvb; c.n[2] = M1;
      c.s[3] = ow + (long)i * M1; c.d[3] = (bf16*)wob; c.n[3] = M1;
      cvt4_k<<<dim3(1024, 4), dim3(256), 0, stream>>>(c);

      // merged Q/K/V convs: z = w*4+b, 768 blocks
      QkvP q{};
      q.W[0] = wqb; q.F[0] = feat + (long)qm[i] * 4 * M1; q.C[0] = Qi;
      q.bias[0] = qb + i * 1024; q.fl[0] = 0;
      q.W[1] = wkb; q.F[1] = feat + (long)km[i] * 4 * M1; q.C[1] = Ki;
      q.bias[1] = kb + i * 1024; q.fl[1] = 0;
      q.W[2] = wvb; q.F[2] = feat + (long)km[i] * 4 * M1; q.C[2] = Vi;
      q.bias[2] = vb + i * 1024; q.fl[2] = 1;
      for (int w = 0; w < 3; w++) { q.Kd[w] = 1024; q.ld[w] = 1024; }
      qkv_kernel<<<dim3(8, 8, 12), dim3(256), 0, stream>>>(q);

      // fused scores+softmax -> P
      attn_sm_k<<<dim3(32), dim3(256), 0, stream>>>(Qi, Ki, (bf16*)P);

      // PV: per (b,h): P[128,128] x Vh[128,1024] -> OAi (C^T pixel-major)
      GemmP pv{}; pv.A = P; pv.B = Vi; pv.C = OAi;
      pv.sA1 = 131072; pv.sA2 = 16384; pv.sB1 = M1; pv.sB2 = 128;
      pv.sC1 = M1; pv.sC2 = 128;
      pv.M = 128; pv.N = 1024; pv.K = 128; pv.lda = 128; pv.ldb = 1024; pv.ldc = 1024;
      pv.Z2 = 8; pv.flags = 1;
      G(dim3(8, 1, 32), pv);

      // O conv, split-K x2, atomic accumulate into cross[qm] (z = b*2+kh)
      GemmP o{}; o.A = wob; o.B = OAi;
      o.C = cross + (long)qm[i] * 4 * M1; o.bias = obv + i * 1024;
      o.sA1 = 0; o.sA2 = 512; o.sB1 = M1; o.sB2 = 512; o.sC1 = M1; o.sC2 = 0;
      o.M = 1024; o.N = 1024; o.K = 512; o.lda = 1024; o.ldb = 1024; o.ldc = 1024;
      o.Z2 = 2; o.flags = 1 | 2 | 8 | 16;
      G(dim3(8, 8, 8), o);
    }
  }

  // 5) SE
  zero_k<<<dim3(48), dim3(256), 0, stream>>>(pooled, 12 * 1024);
  pool_k<<<dim3(192), dim3(256), 0, stream>>>(cross, pooled);
  se_k<<<dim3(12), dim3(256), 0, stream>>>(pooled, sew1, seb1, sew2, seb2, gvec);

  // 6) per-pixel gates + fused
  gatefuse_k<<<dim3(4096), dim3(256), 0, stream>>>(cross, gvec, metrics, gw, gb, (bf16*)fused);

  // 7) fusion conv -> d_out f32 (plain-C)
  {
    cvt_k<<<dim3(9216), dim3(256), 0, stream>>>(fw, (bf16*)fwb, 9L * M1);
    GemmP g{}; g.A = fwb; g.B = fused; g.C = d_out; g.bias = fbias;
    g.sB1 = (long)1024 * 3072; g.sC1 = (long)3072 * 1024;
    g.M = 3072; g.N = 1024; g.K = 3072; g.lda = 3072; g.ldb = 3072; g.ldc = 1024;
    g.Z2 = 1; g.flags = 2;
    G(dim3(8, 24, 4), g);
  }
  (void)in_sizes; (void)n_in; (void)out_size; (void)ws_size;
}

// Round 5
// 1209.737 us; speedup vs baseline: 1.4089x; 1.4089x over previous
//
#include <hip/hip_runtime.h>
#include <hip/hip_bf16.h>

typedef __attribute__((ext_vector_type(8))) short short8;
typedef __attribute__((ext_vector_type(4))) short short4v;
typedef __attribute__((ext_vector_type(4))) float floatx4;
typedef __hip_bfloat16 bf16;

#define M1 1048576L  // 1024*1024

__device__ __forceinline__ void async16(const short* g, short* l) {
  __builtin_amdgcn_global_load_lds((const __attribute__((address_space(1))) void*)g,
                                   (__attribute__((address_space(3))) void*)l, 16, 0, 0);
}

// ------------------------------------------------------- shared GEMM core ---
// 128x128 tile, bf16 MFMA 16x16x32, B transposed ([N][ldb], K-contiguous).
__device__ __forceinline__ void gemm_loop(const short* A, const short* B, int K,
    int lda, int ldb, short* sA, short* sB, int m0, int n0, floatx4 (&acc)[4][4]) {
  const int tid = threadIdx.x, wave = tid >> 6, lane = tid & 63;
  const int lane15 = lane & 15, quad = lane >> 4;
  const int mW = (wave & 1) * 64, nW = (wave >> 1) * 64;
  const int ldrow = lane >> 2, kcol = (lane & 3) * 8;
#pragma unroll
  for (int i = 0; i < 4; i++)
#pragma unroll
    for (int j = 0; j < 4; j++) { floatx4 zz = {0.f, 0.f, 0.f, 0.f}; acc[i][j] = zz; }
  for (int k0 = 0; k0 < K; k0 += 32) {
    __syncthreads();
#pragma unroll
    for (int it = 0; it < 2; it++) {
      const int ca = wave * 2 + it;
      async16(A + (long)(m0 + ca * 16 + ldrow) * lda + k0 + kcol, sA + ca * 512);
      async16(B + (long)(n0 + ca * 16 + ldrow) * ldb + k0 + kcol, sB + ca * 512);
    }
    __syncthreads();
    short8 af[4], bfr[4];
#pragma unroll
    for (int mt = 0; mt < 4; mt++)
      af[mt] = *(const short8*)(sA + (mW + mt * 16 + lane15) * 32 + quad * 8);
#pragma unroll
    for (int nt = 0; nt < 4; nt++)
      bfr[nt] = *(const short8*)(sB + (nW + nt * 16 + lane15) * 32 + quad * 8);
#pragma unroll
    for (int mt = 0; mt < 4; mt++)
#pragma unroll
      for (int nt = 0; nt < 4; nt++)
        acc[mt][nt] = __builtin_amdgcn_mfma_f32_16x16x32_bf16(af[mt], bfr[nt], acc[mt][nt], 0, 0, 0);
  }
}

// flags: 1=C^T  2=f32  4=RMW accumulate (f32 C^T)  32=grid xy swapped
__device__ __forceinline__ void gemm_epi(void* C, const float* bias, long cOff,
    int ldc, int fl, int m0, int n0, floatx4 (&acc)[4][4]) {
  const int lane = threadIdx.x & 63, wave = threadIdx.x >> 6;
  const int lane15 = lane & 15, quad = lane >> 4;
  const int mW = (wave & 1) * 64, nW = (wave >> 1) * 64;
#pragma unroll
  for (int mt = 0; mt < 4; mt++)
#pragma unroll
    for (int nt = 0; nt < 4; nt++) {
      const int mg = m0 + mW + mt * 16 + quad * 4;
      const int ng = n0 + nW + nt * 16 + lane15;
      floatx4 v = acc[mt][nt];
      if (bias) {
        v.x += bias[mg + 0]; v.y += bias[mg + 1];
        v.z += bias[mg + 2]; v.w += bias[mg + 3];
      }
      if (fl & 1) {  // C^T: [N][ldc]
        const long o = cOff + (long)ng * ldc + mg;
        if (fl & 2) {
          float* cp = (float*)C + o;
          if (fl & 4) { v.x += cp[0]; v.y += cp[1]; v.z += cp[2]; v.w += cp[3]; }
          cp[0] = v.x; cp[1] = v.y; cp[2] = v.z; cp[3] = v.w;
        } else {
          bf16* cp = (bf16*)C + o;
          cp[0] = __float2bfloat16(v.x); cp[1] = __float2bfloat16(v.y);
          cp[2] = __float2bfloat16(v.z); cp[3] = __float2bfloat16(v.w);
        }
      } else {       // plain C: [M][ldc]
        const long o = cOff + (long)mg * ldc + ng;
        if (fl & 2) {
          float* cp = (float*)C + o;
          cp[0] = v.x; cp[ldc] = v.y; cp[2L * ldc] = v.z; cp[3L * ldc] = v.w;
        } else {
          bf16* cp = (bf16*)C + o;
          cp[0] = __float2bfloat16(v.x); cp[ldc] = __float2bfloat16(v.y);
          cp[2L * ldc] = __float2bfloat16(v.z); cp[3L * ldc] = __float2bfloat16(v.w);
        }
      }
    }
}

// ------------------------------------------------- generic strided-z GEMM ---
struct GemmP {
  const short* A; const short* B; void* C; const float* bias;
  long sA1, sA2, sB1, sB2, sC1, sC2, sb1, sb2;
  int M, N, K, lda, ldb, ldc, Z2, flags;
};

__global__ __launch_bounds__(256) void gemm_kernel(GemmP p) {
  __shared__ __align__(16) short sA[4096];
  __shared__ __align__(16) short sB[4096];
  const int z = blockIdx.z, z1 = z / p.Z2, z2 = z % p.Z2;
  const short* A = p.A + z1 * p.sA1 + z2 * p.sA2;
  const short* B = p.B + z1 * p.sB1 + z2 * p.sB2;
  const long cOff = z1 * p.sC1 + z2 * p.sC2;
  const float* bias = p.bias;
  if (bias) {
    if ((p.flags & 16) && z2 != 0) bias = 0;
    else bias += z1 * p.sb1 + z2 * p.sb2;
  }
  // flag 32: m-tiles on blockIdx.x (XCD-local A reuse for tall C), n on y.
  int m0, n0;
  if (p.flags & 32) { m0 = blockIdx.x * 128; n0 = blockIdx.y * 128; }
  else              { m0 = blockIdx.y * 128; n0 = blockIdx.x * 128; }
  floatx4 acc[4][4];
  gemm_loop(A, B, p.K, p.lda, p.ldb, sA, sB, m0, n0, acc);
  gemm_epi(p.C, bias, cOff, p.ldc, p.flags, m0, n0, acc);
}

// ------------------------------------- 3-way batched GEMM (proj / QKV) ------
// z = w*4 + b; w selects {W,F,C,bias,flags,K,ld}; b = batch.
struct QkvP {
  const short* W[3]; const short* F[3]; void* C[3]; const float* bias[3];
  int fl[3], Kd[3], ld[3];
};

__global__ __launch_bounds__(256) void qkv_kernel(QkvP q) {
  __shared__ __align__(16) short sA[4096];
  __shared__ __align__(16) short sB[4096];
  const int z = blockIdx.z, w = z >> 2, b = z & 3;
  const int K = q.Kd[w], ld = q.ld[w];
  const short* A = q.W[w];
  const short* B = q.F[w] + (long)b * 1024 * K;
  floatx4 acc[4][4];
  gemm_loop(A, B, K, ld, ld, sA, sB, blockIdx.y * 128, blockIdx.x * 128, acc);
  gemm_epi(q.C[w], q.bias[w], (long)b * M1, 1024, q.fl[w], blockIdx.y * 128, blockIdx.x * 128, acc);
}

// --------------------------- fused scores + softmax (one block per (b,h)) ---
__global__ __launch_bounds__(256) void attn_sm_k(const short* Q, const short* Kt, bf16* P) {
  __shared__ __align__(16) short sA[4096];
  __shared__ __align__(16) short sB[4096];
  __shared__ short S16[128 * 132];
  const int z = blockIdx.x, b = z >> 3, h = z & 7;
  const short* A = Q + (long)b * M1 + (long)h * 131072;
  const short* B = Kt + (long)b * M1 + (long)h * 131072;
  floatx4 acc[4][4];
  gemm_loop(A, B, 1024, 1024, 1024, sA, sB, 0, 0, acc);
  const int lane = threadIdx.x & 63, wave = threadIdx.x >> 6;
  const int lane15 = lane & 15, quad = lane >> 4;
  const int mW = (wave & 1) * 64, nW = (wave >> 1) * 64;
  const float sc = 0.08838834764831845f;   // 128^-0.5
#pragma unroll
  for (int mt = 0; mt < 4; mt++)
#pragma unroll
    for (int nt = 0; nt < 4; nt++) {
      const int mg = mW + mt * 16 + quad * 4, ng = nW + nt * 16 + lane15;
      floatx4 v = acc[mt][nt];
      *(bf16*)&S16[(mg + 0) * 132 + ng] = __float2bfloat16(v.x * sc);
      *(bf16*)&S16[(mg + 1) * 132 + ng] = __float2bfloat16(v.y * sc);
      *(bf16*)&S16[(mg + 2) * 132 + ng] = __float2bfloat16(v.z * sc);
      *(bf16*)&S16[(mg + 3) * 132 + ng] = __float2bfloat16(v.w * sc);
    }
  __syncthreads();
  bf16* Pb = P + (long)z * 16384;
  for (int r = wave * 32; r < wave * 32 + 32; r++) {
    float a = __bfloat162float(*(bf16*)&S16[r * 132 + lane]);
    float c = __bfloat162float(*(bf16*)&S16[r * 132 + lane + 64]);
    float m = fmaxf(a, c);
    for (int off = 32; off; off >>= 1) m = fmaxf(m, __shfl_xor(m, off));
    float e0 = expf(a - m), e1 = expf(c - m), s = e0 + e1;
    for (int off = 32; off; off >>= 1) s += __shfl_xor(s, off);
    const float inv = 1.0f / s;
    Pb[r * 128 + lane] = __float2bfloat16(e0 * inv);
    Pb[r * 128 + lane + 64] = __float2bfloat16(e1 * inv);
  }
}

// -------------------------------------------------------- f32 -> bf16 -------
__global__ void cvt_k(const float* src, bf16* dst, long n) {
  long i = ((long)blockIdx.x * 256 + threadIdx.x) * 4;
  if (i + 3 < n) {
    float4 v = *(const float4*)(src + i);
    bf16 t[4] = {__float2bfloat16(v.x), __float2bfloat16(v.y),
                 __float2bfloat16(v.z), __float2bfloat16(v.w)};
    *(short4v*)(dst + i) = *(short4v*)t;
  }
}

struct Cvt4 { const float* s[4]; bf16* d[4]; long n[4]; };
__global__ void cvt4_k(Cvt4 c) {
  const int seg = blockIdx.y;
  long i = ((long)blockIdx.x * 256 + threadIdx.x) * 4;
  if (i + 3 < c.n[seg]) {
    float4 v = *(const float4*)(c.s[seg] + i);
    bf16 t[4] = {__float2bfloat16(v.x), __float2bfloat16(v.y),
                 __float2bfloat16(v.z), __float2bfloat16(v.w)};
    *(short4v*)(c.d[seg] + i) = *(short4v*)t;
  }
}

// ------------------------------------------------------------ transpose -----
__global__ void trans_k(const float* in, bf16* out, int C, int D) {
  __shared__ float tile[32][33];
  const int d0 = blockIdx.x * 32, c0 = blockIdx.y * 32, b = blockIdx.z;
  const float* ib = in + (long)b * C * D;
  bf16* ob = out + (long)b * C * D;
  for (int i = threadIdx.y; i < 32; i += 8)
    tile[i][threadIdx.x] = ib[(long)(c0 + i) * D + d0 + threadIdx.x];
  __syncthreads();
  for (int i = threadIdx.y; i < 32; i += 8)
    ob[(long)(d0 + i) * C + c0 + threadIdx.x] = __float2bfloat16(tile[threadIdx.x][i]);
}

// ------------------------------------------------------ l2norm + metrics ----
__global__ __launch_bounds__(256) void norm_k(float* cross, bf16* feat, float* metrics) {
  const int blk = blockIdx.x;     // mod*4096 + pix
  const int mod = blk >> 12;
  float* base = cross + (long)blk * 1024;
  bf16* fb = feat + (long)blk * 1024;
  const int t = threadIdx.x;
  float v[4]; float ssq = 0.f;
#pragma unroll
  for (int j = 0; j < 4; j++) { v[j] = base[t + j * 256]; ssq += v[j] * v[j]; }
  __shared__ float r1[256], r2[256], r3[256];
  __shared__ float sinv;
  r1[t] = ssq; __syncthreads();
  for (int s = 128; s > 0; s >>= 1) { if (t < s) r1[t] += r1[t + s]; __syncthreads(); }
  if (t == 0) sinv = 1.0f / fmaxf(sqrtf(r1[0]), 1e-12f);
  __syncthreads();
  const float invn = sinv;
  float s1 = 0.f, s2 = 0.f, zc = 0.f;
#pragma unroll
  for (int j = 0; j < 4; j++) {
    float x = v[j] * invn; v[j] = x;
    s1 += x; s2 += x * x; if (x == 0.0f) zc += 1.0f;
  }
  r1[t] = s1; r2[t] = s2; r3[t] = zc; __syncthreads();
  for (int s = 128; s > 0; s >>= 1) {
    if (t < s) { r1[t] += r1[t + s]; r2[t] += r2[t + s]; r3[t] += r3[t + s]; }
    __syncthreads();
  }
  if (t == 0) {
    float m = (mod == 0) ? (r2[0] - r1[0] * r1[0] * (1.0f / 1024.f)) * (1.0f / 1023.f)
                         : r3[0] * (1.0f / 1024.f);
    metrics[blk] = m;
  }
#pragma unroll
  for (int j = 0; j < 4; j++) { base[t + j * 256] = v[j]; fb[t + j * 256] = __float2bfloat16(v[j]); }
}

// ----------------------------------------------------------------- SE -------
__global__ void zero_k(float* p, int n) {
  int i = blockIdx.x * 256 + threadIdx.x;
  if (i < n) p[i] = 0.f;
}

__global__ void pool_k(const float* cross, float* pooled) {
  const int blk = blockIdx.x;          // mb*16 + seg, mb = mod*4+b
  const int seg = blk & 15, mb = blk >> 4;
  const float* base = cross + (long)mb * M1 + (long)seg * 64 * 1024;
  float* pout = pooled + (long)mb * 1024;
  for (int c = threadIdx.x; c < 1024; c += 256) {
    float s = 0.f;
    for (int d = 0; d < 64; d++) s += base[(long)d * 1024 + c];
    atomicAdd(&pout[c], s * (1.0f / 1024.0f));
  }
}

__global__ void se_k(const float* pooled, const float* w1, const float* b1,
                     const float* w2, const float* b2, float* gvec) {
  const int mb = blockIdx.x, mod = mb >> 2, t = threadIdx.x;
  __shared__ float ps[1024]; __shared__ float hs[64];
  const float* p = pooled + (long)mb * 1024;
  for (int c = t; c < 1024; c += 256) ps[c] = p[c];
  __syncthreads();
  if (t < 64) {
    const float* wr = w1 + (long)(mod * 64 + t) * 1024;
    float s = 0.f;
    for (int c = 0; c < 1024; c++) s += wr[c] * ps[c];
    s += b1[mod * 64 + t];
    hs[t] = fmaxf(s, 0.f);
  }
  __syncthreads();
  for (int o = t; o < 1024; o += 256) {
    const float* wr = w2 + (long)(mod * 1024 + o) * 64;
    float s = 0.f;
    for (int j = 0; j < 64; j++) s += wr[j] * hs[j];
    s += b2[mod * 1024 + o];
    gvec[(long)mb * 1024 + o] = 1.0f / (1.0f + expf(-s));
  }
}

// ------------------------------------------------------- gates + fused ------
__global__ __launch_bounds__(256) void gatefuse_k(const float* cross, const float* gvec,
    const float* metrics, const float* gw, const float* gb, bf16* fused) {
  const int pix = blockIdx.x;          // b*1024 + d
  const int b = pix >> 10, t = threadIdx.x;
  __shared__ float refbuf[3072];
  __shared__ float red[3][256];
  __shared__ float gsh[3];
  float p0 = 0.f, p1 = 0.f, p2 = 0.f;
  for (int mod = 0; mod < 3; mod++) {
    const float* cb = cross + ((long)mod * 4096 + pix) * 1024;
    const float* gv = gvec + (long)(mod * 4 + b) * 1024;
    for (int c = t; c < 1024; c += 256) {
      float val = cb[c] * gv[c];
      refbuf[mod * 1024 + c] = val;
      p0 += gw[0 * 3075 + mod * 1024 + c] * val;
      p1 += gw[1 * 3075 + mod * 1024 + c] * val;
      p2 += gw[2 * 3075 + mod * 1024 + c] * val;
    }
  }
  red[0][t] = p0; red[1][t] = p1; red[2][t] = p2; __syncthreads();
  for (int s = 128; s > 0; s >>= 1) {
    if (t < s) { red[0][t] += red[0][t + s]; red[1][t] += red[1][t + s]; red[2][t] += red[2][t + s]; }
    __syncthreads();
  }
  if (t == 0) {
    const float var = metrics[pix], spd = metrics[4096 + pix], spl = metrics[8192 + pix];
    for (int j = 0; j < 3; j++) {
      float s = red[j][0] + gw[j * 3075 + 3072] * var + gw[j * 3075 + 3073] * spd
              + gw[j * 3075 + 3074] * spl + gb[j];
      gsh[j] = 1.0f / (1.0f + expf(-s));
    }
  }
  __syncthreads();
  bf16* fb = fused + (long)pix * 3072;
  for (int i = t; i < 3072; i += 256) fb[i] = __float2bfloat16(refbuf[i] * gsh[i >> 10]);
}

// ---------------------------------------------------------------- host ------
extern "C" void kernel_launch(void* const* d_in, const int* in_sizes, int n_in,
                              void* d_out, int out_size, void* d_ws, size_t ws_size,
                              hipStream_t stream) {
  const float* rgb = (const float*)d_in[0];
  const float* dep = (const float*)d_in[1];
  const float* lid = (const float*)d_in[2];
  const float* pw[3] = {(const float*)d_in[3], (const float*)d_in[5], (const float*)d_in[7]};
  const float* pb[3] = {(const float*)d_in[4], (const float*)d_in[6], (const float*)d_in[8]};
  const float* qw = (const float*)d_in[9];  const float* qb = (const float*)d_in[10];
  const float* kw = (const float*)d_in[11]; const float* kb = (const float*)d_in[12];
  const float* vw = (const float*)d_in[13]; const float* vb = (const float*)d_in[14];
  const float* ow = (const float*)d_in[15]; const float* obv = (const float*)d_in[16];
  const float* sew1 = (const float*)d_in[17]; const float* seb1 = (const float*)d_in[18];
  const float* sew2 = (const float*)d_in[19]; const float* seb2 = (const float*)d_in[20];
  const float* gw = (const float*)d_in[21];   const float* gb = (const float*)d_in[22];
  const float* fw = (const float*)d_in[23]; const float* fbias = (const float*)d_in[24];

  // ---- workspace: ~107 MB peak (lifetime-aliased; proven safe) ----
  char* wp = (char*)d_ws;
  auto carve = [&](size_t bytes) -> char* {
    char* r = wp; wp += (bytes + 255) & ~(size_t)255; return r;
  };
  float* cross = (float*)carve(12L * M1 * 4);    // [3][4][1024 d][1024 c] f32, persists
  short* feat  = (short*)carve(12L * M1 * 2);    // bf16 normalized feats; dead after attn -> fwb
  char*  S     = carve(35L * 1024 * 1024);       // shared scratch region
  float* metrics = (float*)carve(3L * 4096 * 4);
  float* pooled  = (float*)carve(12L * 1024 * 4);
  float* gvec    = (float*)carve(12L * 1024 * 4);

  // S phase 1 (dead after projections):
  short* rgbT = (short*)S;                          // 4 MB  [4][1024 d][512 c]
  short* depT = (short*)(S + 4L  * 1024 * 1024);    // 2 MB
  short* lidT = (short*)(S + 6L  * 1024 * 1024);    // 0.5 MB
  short* pwb[3] = {(short*)(S + 8L * 1024 * 1024),
                   (short*)(S + 9L * 1024 * 1024),
                   (short*)(S + 9728L * 1024)};
  // S phase 2 (per attention block i):
  short* Qi  = (short*)S;                           // 8 MB [4][1024 c][1024 d]
  short* Ki  = (short*)(S + 8L  * 1024 * 1024);     // 8 MB
  short* Vi  = (short*)(S + 16L * 1024 * 1024);     // 8 MB [4][1024 d][1024 c]
  short* OAi = (short*)(S + 24L * 1024 * 1024);     // 8 MB
  short* wqb = (short*)(S + 24L * 1024 * 1024);     // 2 MB (OAi slot; dead until PV)
  short* wkb = (short*)(S + 26L * 1024 * 1024);     // 2 MB
  short* wvb = (short*)(S + 28L * 1024 * 1024);     // 2 MB
  short* wob = (short*)(S + 32L * 1024 * 1024);     // 2 MB (survives PV)
  short* P   = (short*)(S + 34L * 1024 * 1024);     // 1 MB bf16 [32][128][128]
  // S phase 3:
  short* fused = (short*)S;                         // 24 MB [4][1024 d][3072 c]
  short* fwb   = feat;                              // 18 MB (feat slot)

  auto G = [&](dim3 grid, GemmP g) { gemm_kernel<<<grid, dim3(256), 0, stream>>>(g); };

  // 1) transpose+convert raw inputs [B,C,D] f32 -> [B,D,C] bf16
  trans_k<<<dim3(32, 16, 4), dim3(32, 8), 0, stream>>>(rgb, (bf16*)rgbT, 512, 1024);
  trans_k<<<dim3(32, 8, 4),  dim3(32, 8), 0, stream>>>(dep, (bf16*)depT, 256, 1024);
  trans_k<<<dim3(32, 2, 4),  dim3(32, 8), 0, stream>>>(lid, (bf16*)lidT, 64, 1024);

  // 2) proj weights -> bf16, then merged proj GEMM (z=12)
  {
    Cvt4 c{};
    c.s[0] = pw[0]; c.d[0] = (bf16*)pwb[0]; c.n[0] = 1024L * 512;
    c.s[1] = pw[1]; c.d[1] = (bf16*)pwb[1]; c.n[1] = 1024L * 256;
    c.s[2] = pw[2]; c.d[2] = (bf16*)pwb[2]; c.n[2] = 1024L * 64;
    c.s[3] = pw[2]; c.d[3] = (bf16*)pwb[2]; c.n[3] = 0;
    cvt4_k<<<dim3(512, 4), dim3(256), 0, stream>>>(c);

    QkvP q{};
    const int Ks[3] = {512, 256, 64};
    const short* Bts[3] = {rgbT, depT, lidT};
    for (int m = 0; m < 3; m++) {
      q.W[m] = pwb[m]; q.F[m] = Bts[m]; q.C[m] = cross + (long)m * 4 * M1;
      q.bias[m] = pb[m]; q.fl[m] = 1 | 2; q.Kd[m] = Ks[m]; q.ld[m] = Ks[m];
    }
    qkv_kernel<<<dim3(8, 8, 12), dim3(256), 0, stream>>>(q);
  }

  // 3) l2norm (in-place) + bf16 feat copy + quality metrics
  norm_k<<<dim3(12288), dim3(256), 0, stream>>>(cross, (bf16*)feat, metrics);

  // 4) attention blocks one at a time
  {
    const int qm[6] = {0, 0, 1, 1, 2, 2};
    const int km[6] = {1, 2, 0, 2, 0, 1};
    for (int i = 0; i < 6; i++) {
      Cvt4 c{};
      c.s[0] = qw + (long)i * M1; c.d[0] = (bf16*)wqb; c.n[0] = M1;
      c.s[1] = kw + (long)i * M1; c.d[1] = (bf16*)wkb; c.n[1] = M1;
      c.s[2] = vw + (long)i * M1; c.d[2] = (bf16*)wvb; c.n[2] = M1;
      c.s[3] = ow + (long)i * M1; c.d[3] = (bf16*)wob; c.n[3] = M1;
      cvt4_k<<<dim3(1024, 4), dim3(256), 0, stream>>>(c);

      // merged Q/K/V convs: z = w*4+b, 768 blocks
      QkvP q{};
      q.W[0] = wqb; q.F[0] = feat + (long)qm[i] * 4 * M1; q.C[0] = Qi;
      q.bias[0] = qb + i * 1024; q.fl[0] = 0;
      q.W[1] = wkb; q.F[1] = feat + (long)km[i] * 4 * M1; q.C[1] = Ki;
      q.bias[1] = kb + i * 1024; q.fl[1] = 0;
      q.W[2] = wvb; q.F[2] = feat + (long)km[i] * 4 * M1; q.C[2] = Vi;
      q.bias[2] = vb + i * 1024; q.fl[2] = 1;
      for (int w = 0; w < 3; w++) { q.Kd[w] = 1024; q.ld[w] = 1024; }
      qkv_kernel<<<dim3(8, 8, 12), dim3(256), 0, stream>>>(q);

      // fused scores+softmax -> P
      attn_sm_k<<<dim3(32), dim3(256), 0, stream>>>(Qi, Ki, (bf16*)P);

      // PV: per (b,h): P[128,128] x Vh[128,1024] -> OAi (C^T pixel-major)
      GemmP pv{}; pv.A = P; pv.B = Vi; pv.C = OAi;
      pv.sA1 = 131072; pv.sA2 = 16384; pv.sB1 = M1; pv.sB2 = 128;
      pv.sC1 = M1; pv.sC2 = 128;
      pv.M = 128; pv.N = 1024; pv.K = 128; pv.lda = 128; pv.ldb = 1024; pv.ldc = 1024;
      pv.Z2 = 8; pv.flags = 1;
      G(dim3(8, 1, 32), pv);

      // O conv: cross[qm] += W_o[i] @ OAi + b_o[i]  (plain f32 C^T RMW)
      GemmP o{}; o.A = wob; o.B = OAi;
      o.C = cross + (long)qm[i] * 4 * M1; o.bias = obv + i * 1024;
      o.sB1 = M1; o.sC1 = M1;
      o.M = 1024; o.N = 1024; o.K = 1024; o.lda = 1024; o.ldb = 1024; o.ldc = 1024;
      o.Z2 = 1; o.flags = 1 | 2 | 4;
      G(dim3(8, 8, 4), o);
    }
  }

  // 5) SE
  zero_k<<<dim3(48), dim3(256), 0, stream>>>(pooled, 12 * 1024);
  pool_k<<<dim3(192), dim3(256), 0, stream>>>(cross, pooled);
  se_k<<<dim3(12), dim3(256), 0, stream>>>(pooled, sew1, seb1, sew2, seb2, gvec);

  // 6) per-pixel gates + fused
  gatefuse_k<<<dim3(4096), dim3(256), 0, stream>>>(cross, gvec, metrics, gw, gb, (bf16*)fused);

  // 7) fusion conv -> d_out f32 (plain-C); m-tiles on blockIdx.x (flag 32)
  // so each XCD keeps a 3-m-tile strip of the 18 MB weight resident in its L2.
  {
    cvt_k<<<dim3(9216), dim3(256), 0, stream>>>(fw, (bf16*)fwb, 9L * M1);
    GemmP g{}; g.A = fwb; g.B = fused; g.C = d_out; g.bias = fbias;
    g.sB1 = (long)1024 * 3072; g.sC1 = (long)3072 * 1024;
    g.M = 3072; g.N = 1024; g.K = 3072; g.lda = 3072; g.ldb = 3072; g.ldc = 1024;
    g.Z2 = 1; g.flags = 2 | 32;
    G(dim3(24, 8, 4), g);
  }
  (void)in_sizes; (void)n_in; (void)out_size; (void)ws_size;
}

// Round 6
// 1152.076 us; speedup vs baseline: 1.4794x; 1.0500x over previous
//
#include <hip/hip_runtime.h>
#include <hip/hip_bf16.h>

typedef __attribute__((ext_vector_type(8))) short short8;
typedef __attribute__((ext_vector_type(4))) short short4v;
typedef __attribute__((ext_vector_type(4))) float floatx4;
typedef __hip_bfloat16 bf16;

#define M1 1048576L  // 1024*1024
#define MB (1024L * 1024L)

__device__ __forceinline__ void async16(const short* g, short* l) {
  __builtin_amdgcn_global_load_lds((const __attribute__((address_space(1))) void*)g,
                                   (__attribute__((address_space(3))) void*)l, 16, 0, 0);
}

// ------------------------------------------------------- shared GEMM core ---
// 128x128 tile, bf16 MFMA 16x16x32, B transposed ([N][ldb], K-contiguous).
// XOR-swizzled LDS: lane (row r, kquad q) stages global quad q^((r>>1)&3) so
// fragment reads hit each 4-bank group exactly twice (2-way = free, m136);
// without it the 64-B row stride makes 8-way conflicts (2.94x LDS time).
__device__ __forceinline__ void gemm_loop(const short* A, const short* B, int K,
    int lda, int ldb, short* sA, short* sB, int m0, int n0, floatx4 (&acc)[4][4]) {
  const int tid = threadIdx.x, wave = tid >> 6, lane = tid & 63;
  const int lane15 = lane & 15, quad = lane >> 4;
  const int mW = (wave & 1) * 64, nW = (wave >> 1) * 64;
  const int row4 = lane >> 2;                         // row within 16-row chunk
  const int kcol = ((lane & 3) ^ ((row4 >> 1) & 3)) * 8;  // swizzled k-quad fetch
  const int psw = (lane15 >> 1) & 3;                  // read-side swizzle
#pragma unroll
  for (int i = 0; i < 4; i++)
#pragma unroll
    for (int j = 0; j < 4; j++) { floatx4 zz = {0.f, 0.f, 0.f, 0.f}; acc[i][j] = zz; }
  for (int k0 = 0; k0 < K; k0 += 32) {
    __syncthreads();
#pragma unroll
    for (int it = 0; it < 2; it++) {
      const int ca = wave * 2 + it;
      async16(A + (long)(m0 + ca * 16 + row4) * lda + k0 + kcol, sA + ca * 512);
      async16(B + (long)(n0 + ca * 16 + row4) * ldb + k0 + kcol, sB + ca * 512);
    }
    __syncthreads();
    short8 af[4], bfr[4];
#pragma unroll
    for (int mt = 0; mt < 4; mt++)
      af[mt] = *(const short8*)(sA + (mW + mt * 16 + lane15) * 32 + (quad ^ psw) * 8);
#pragma unroll
    for (int nt = 0; nt < 4; nt++)
      bfr[nt] = *(const short8*)(sB + (nW + nt * 16 + lane15) * 32 + (quad ^ psw) * 8);
#pragma unroll
    for (int mt = 0; mt < 4; mt++)
#pragma unroll
      for (int nt = 0; nt < 4; nt++)
        acc[mt][nt] = __builtin_amdgcn_mfma_f32_16x16x32_bf16(af[mt], bfr[nt], acc[mt][nt], 0, 0, 0);
  }
}

// flags: 1=C^T  2=f32  4=RMW accumulate (f32 C^T)  32=grid xy swapped
__device__ __forceinline__ void gemm_epi(void* C, const float* bias, long cOff,
    int ldc, int fl, int m0, int n0, floatx4 (&acc)[4][4]) {
  const int lane = threadIdx.x & 63, wave = threadIdx.x >> 6;
  const int lane15 = lane & 15, quad = lane >> 4;
  const int mW = (wave & 1) * 64, nW = (wave >> 1) * 64;
#pragma unroll
  for (int mt = 0; mt < 4; mt++)
#pragma unroll
    for (int nt = 0; nt < 4; nt++) {
      const int mg = m0 + mW + mt * 16 + quad * 4;
      const int ng = n0 + nW + nt * 16 + lane15;
      floatx4 v = acc[mt][nt];
      if (bias) {
        v.x += bias[mg + 0]; v.y += bias[mg + 1];
        v.z += bias[mg + 2]; v.w += bias[mg + 3];
      }
      if (fl & 1) {  // C^T: [N][ldc]
        const long o = cOff + (long)ng * ldc + mg;
        if (fl & 2) {
          float* cp = (float*)C + o;
          if (fl & 4) { v.x += cp[0]; v.y += cp[1]; v.z += cp[2]; v.w += cp[3]; }
          cp[0] = v.x; cp[1] = v.y; cp[2] = v.z; cp[3] = v.w;
        } else {
          bf16* cp = (bf16*)C + o;
          cp[0] = __float2bfloat16(v.x); cp[1] = __float2bfloat16(v.y);
          cp[2] = __float2bfloat16(v.z); cp[3] = __float2bfloat16(v.w);
        }
      } else {       // plain C: [M][ldc]
        const long o = cOff + (long)mg * ldc + ng;
        if (fl & 2) {
          float* cp = (float*)C + o;
          cp[0] = v.x; cp[ldc] = v.y; cp[2L * ldc] = v.z; cp[3L * ldc] = v.w;
        } else {
          bf16* cp = (bf16*)C + o;
          cp[0] = __float2bfloat16(v.x); cp[ldc] = __float2bfloat16(v.y);
          cp[2L * ldc] = __float2bfloat16(v.z); cp[3L * ldc] = __float2bfloat16(v.w);
        }
      }
    }
}

// ------------------------------------------------- generic strided-z GEMM ---
struct GemmP {
  const short* A; const short* B; void* C; const float* bias;
  long sA1, sA2, sB1, sB2, sC1, sC2, sb1, sb2;
  int M, N, K, lda, ldb, ldc, Z2, flags;
};

__global__ __launch_bounds__(256) void gemm_kernel(GemmP p) {
  __shared__ __align__(16) short sA[4096];
  __shared__ __align__(16) short sB[4096];
  const int z = blockIdx.z, z1 = z / p.Z2, z2 = z % p.Z2;
  const short* A = p.A + z1 * p.sA1 + z2 * p.sA2;
  const short* B = p.B + z1 * p.sB1 + z2 * p.sB2;
  const long cOff = z1 * p.sC1 + z2 * p.sC2;
  const float* bias = p.bias;
  if (bias) bias += z1 * p.sb1 + z2 * p.sb2;
  int m0, n0;
  if (p.flags & 32) { m0 = blockIdx.x * 128; n0 = blockIdx.y * 128; }
  else              { m0 = blockIdx.y * 128; n0 = blockIdx.x * 128; }
  floatx4 acc[4][4];
  gemm_loop(A, B, p.K, p.lda, p.ldb, sA, sB, m0, n0, acc);
  gemm_epi(p.C, bias, cOff, p.ldc, p.flags, m0, n0, acc);
}

// -------------------------------- 4-way batched GEMM (proj / QKV [+O]) ------
// z = w*4 + b; w selects slot; b = batch. B = F[w] + b*1024*K[w];
// C offset = b*M1 (elements of C dtype).
struct QkvP {
  const short* W[4]; const short* F[4]; void* C[4]; const float* bias[4];
  int fl[4], Kd[4], ld[4];
};

__global__ __launch_bounds__(256) void qkv_kernel(QkvP q) {
  __shared__ __align__(16) short sA[4096];
  __shared__ __align__(16) short sB[4096];
  const int z = blockIdx.z, w = z >> 2, b = z & 3;
  const int K = q.Kd[w], ld = q.ld[w];
  const short* A = q.W[w];
  const short* B = q.F[w] + (long)b * 1024 * K;
  floatx4 acc[4][4];
  gemm_loop(A, B, K, ld, ld, sA, sB, blockIdx.y * 128, blockIdx.x * 128, acc);
  gemm_epi(q.C[w], q.bias[w], (long)b * M1, 1024, q.fl[w], blockIdx.y * 128, blockIdx.x * 128, acc);
}

// --------------------------- fused scores + softmax (one block per (b,h)) ---
__global__ __launch_bounds__(256) void attn_sm_k(const short* Q, const short* Kt, bf16* P) {
  __shared__ __align__(16) short sA[4096];
  __shared__ __align__(16) short sB[4096];
  __shared__ short S16[128 * 132];
  const int z = blockIdx.x, b = z >> 3, h = z & 7;
  const short* A = Q + (long)b * M1 + (long)h * 131072;
  const short* B = Kt + (long)b * M1 + (long)h * 131072;
  floatx4 acc[4][4];
  gemm_loop(A, B, 1024, 1024, 1024, sA, sB, 0, 0, acc);
  const int lane = threadIdx.x & 63, wave = threadIdx.x >> 6;
  const int lane15 = lane & 15, quad = lane >> 4;
  const int mW = (wave & 1) * 64, nW = (wave >> 1) * 64;
  const float sc = 0.08838834764831845f;   // 128^-0.5
#pragma unroll
  for (int mt = 0; mt < 4; mt++)
#pragma unroll
    for (int nt = 0; nt < 4; nt++) {
      const int mg = mW + mt * 16 + quad * 4, ng = nW + nt * 16 + lane15;
      floatx4 v = acc[mt][nt];
      *(bf16*)&S16[(mg + 0) * 132 + ng] = __float2bfloat16(v.x * sc);
      *(bf16*)&S16[(mg + 1) * 132 + ng] = __float2bfloat16(v.y * sc);
      *(bf16*)&S16[(mg + 2) * 132 + ng] = __float2bfloat16(v.z * sc);
      *(bf16*)&S16[(mg + 3) * 132 + ng] = __float2bfloat16(v.w * sc);
    }
  __syncthreads();
  bf16* Pb = P + (long)z * 16384;
  for (int r = wave * 32; r < wave * 32 + 32; r++) {
    float a = __bfloat162float(*(bf16*)&S16[r * 132 + lane]);
    float c = __bfloat162float(*(bf16*)&S16[r * 132 + lane + 64]);
    float m = fmaxf(a, c);
    for (int off = 32; off; off >>= 1) m = fmaxf(m, __shfl_xor(m, off));
    float e0 = expf(a - m), e1 = expf(c - m), s = e0 + e1;
    for (int off = 32; off; off >>= 1) s += __shfl_xor(s, off);
    const float inv = 1.0f / s;
    Pb[r * 128 + lane] = __float2bfloat16(e0 * inv);
    Pb[r * 128 + lane + 64] = __float2bfloat16(e1 * inv);
  }
}

// -------------------------------------------------------- f32 -> bf16 -------
__global__ void cvt_k(const float* src, bf16* dst, long n) {
  long i = ((long)blockIdx.x * 256 + threadIdx.x) * 4;
  if (i + 3 < n) {
    float4 v = *(const float4*)(src + i);
    bf16 t[4] = {__float2bfloat16(v.x), __float2bfloat16(v.y),
                 __float2bfloat16(v.z), __float2bfloat16(v.w)};
    *(short4v*)(dst + i) = *(short4v*)t;
  }
}

struct Cvt4 { const float* s[4]; bf16* d[4]; long n[4]; };
__global__ void cvt4_k(Cvt4 c) {
  const int seg = blockIdx.y;
  long i = ((long)blockIdx.x * 256 + threadIdx.x) * 4;
  if (i + 3 < c.n[seg]) {
    float4 v = *(const float4*)(c.s[seg] + i);
    bf16 t[4] = {__float2bfloat16(v.x), __float2bfloat16(v.y),
                 __float2bfloat16(v.z), __float2bfloat16(v.w)};
    *(short4v*)(c.d[seg] + i) = *(short4v*)t;
  }
}

// ------------------------------------------------------------ transpose -----
__global__ void trans_k(const float* in, bf16* out, int C, int D) {
  __shared__ float tile[32][33];
  const int d0 = blockIdx.x * 32, c0 = blockIdx.y * 32, b = blockIdx.z;
  const float* ib = in + (long)b * C * D;
  bf16* ob = out + (long)b * C * D;
  for (int i = threadIdx.y; i < 32; i += 8)
    tile[i][threadIdx.x] = ib[(long)(c0 + i) * D + d0 + threadIdx.x];
  __syncthreads();
  for (int i = threadIdx.y; i < 32; i += 8)
    ob[(long)(d0 + i) * C + c0 + threadIdx.x] = __float2bfloat16(tile[threadIdx.x][i]);
}

// ------------------------------------------------------ l2norm + metrics ----
__global__ __launch_bounds__(256) void norm_k(float* cross, bf16* feat, float* metrics) {
  const int blk = blockIdx.x;     // mod*4096 + pix
  const int mod = blk >> 12;
  float* base = cross + (long)blk * 1024;
  bf16* fb = feat + (long)blk * 1024;
  const int t = threadIdx.x;
  float v[4]; float ssq = 0.f;
#pragma unroll
  for (int j = 0; j < 4; j++) { v[j] = base[t + j * 256]; ssq += v[j] * v[j]; }
  __shared__ float r1[256], r2[256], r3[256];
  __shared__ float sinv;
  r1[t] = ssq; __syncthreads();
  for (int s = 128; s > 0; s >>= 1) { if (t < s) r1[t] += r1[t + s]; __syncthreads(); }
  if (t == 0) sinv = 1.0f / fmaxf(sqrtf(r1[0]), 1e-12f);
  __syncthreads();
  const float invn = sinv;
  float s1 = 0.f, s2 = 0.f, zc = 0.f;
#pragma unroll
  for (int j = 0; j < 4; j++) {
    float x = v[j] * invn; v[j] = x;
    s1 += x; s2 += x * x; if (x == 0.0f) zc += 1.0f;
  }
  r1[t] = s1; r2[t] = s2; r3[t] = zc; __syncthreads();
  for (int s = 128; s > 0; s >>= 1) {
    if (t < s) { r1[t] += r1[t + s]; r2[t] += r2[t + s]; r3[t] += r3[t + s]; }
    __syncthreads();
  }
  if (t == 0) {
    float m = (mod == 0) ? (r2[0] - r1[0] * r1[0] * (1.0f / 1024.f)) * (1.0f / 1023.f)
                         : r3[0] * (1.0f / 1024.f);
    metrics[blk] = m;
  }
#pragma unroll
  for (int j = 0; j < 4; j++) { base[t + j * 256] = v[j]; fb[t + j * 256] = __float2bfloat16(v[j]); }
}

// ----------------------------------------------------------------- SE -------
__global__ void zero_k(float* p, int n) {
  int i = blockIdx.x * 256 + threadIdx.x;
  if (i < n) p[i] = 0.f;
}

__global__ void pool_k(const float* cross, float* pooled) {
  const int blk = blockIdx.x;          // mb*16 + seg, mb = mod*4+b
  const int seg = blk & 15, mb = blk >> 4;
  const float* base = cross + (long)mb * M1 + (long)seg * 64 * 1024;
  float* pout = pooled + (long)mb * 1024;
  for (int c = threadIdx.x; c < 1024; c += 256) {
    float s = 0.f;
    for (int d = 0; d < 64; d++) s += base[(long)d * 1024 + c];
    atomicAdd(&pout[c], s * (1.0f / 1024.0f));
  }
}

__global__ void se_k(const float* pooled, const float* w1, const float* b1,
                     const float* w2, const float* b2, float* gvec) {
  const int mb = blockIdx.x, mod = mb >> 2, t = threadIdx.x;
  __shared__ float ps[1024]; __shared__ float hs[64];
  const float* p = pooled + (long)mb * 1024;
  for (int c = t; c < 1024; c += 256) ps[c] = p[c];
  __syncthreads();
  if (t < 64) {
    const float* wr = w1 + (long)(mod * 64 + t) * 1024;
    float s = 0.f;
    for (int c = 0; c < 1024; c++) s += wr[c] * ps[c];
    s += b1[mod * 64 + t];
    hs[t] = fmaxf(s, 0.f);
  }
  __syncthreads();
  for (int o = t; o < 1024; o += 256) {
    const float* wr = w2 + (long)(mod * 1024 + o) * 64;
    float s = 0.f;
    for (int j = 0; j < 64; j++) s += wr[j] * hs[j];
    s += b2[mod * 1024 + o];
    gvec[(long)mb * 1024 + o] = 1.0f / (1.0f + expf(-s));
  }
}

// ------------------------------------------------------- gates + fused ------
__global__ __launch_bounds__(256) void gatefuse_k(const float* cross, const float* gvec,
    const float* metrics, const float* gw, const float* gb, bf16* fused) {
  const int pix = blockIdx.x;          // b*1024 + d
  const int b = pix >> 10, t = threadIdx.x;
  __shared__ float refbuf[3072];
  __shared__ float red[3][256];
  __shared__ float gsh[3];
  float p0 = 0.f, p1 = 0.f, p2 = 0.f;
  for (int mod = 0; mod < 3; mod++) {
    const float* cb = cross + ((long)mod * 4096 + pix) * 1024;
    const float* gv = gvec + (long)(mod * 4 + b) * 1024;
    for (int c = t; c < 1024; c += 256) {
      float val = cb[c] * gv[c];
      refbuf[mod * 1024 + c] = val;
      p0 += gw[0 * 3075 + mod * 1024 + c] * val;
      p1 += gw[1 * 3075 + mod * 1024 + c] * val;
      p2 += gw[2 * 3075 + mod * 1024 + c] * val;
    }
  }
  red[0][t] = p0; red[1][t] = p1; red[2][t] = p2; __syncthreads();
  for (int s = 128; s > 0; s >>= 1) {
    if (t < s) { red[0][t] += red[0][t + s]; red[1][t] += red[1][t + s]; red[2][t] += red[2][t + s]; }
    __syncthreads();
  }
  if (t == 0) {
    const float var = metrics[pix], spd = metrics[4096 + pix], spl = metrics[8192 + pix];
    for (int j = 0; j < 3; j++) {
      float s = red[j][0] + gw[j * 3075 + 3072] * var + gw[j * 3075 + 3073] * spd
              + gw[j * 3075 + 3074] * spl + gb[j];
      gsh[j] = 1.0f / (1.0f + expf(-s));
    }
  }
  __syncthreads();
  bf16* fb = fused + (long)pix * 3072;
  for (int i = t; i < 3072; i += 256) fb[i] = __float2bfloat16(refbuf[i] * gsh[i >> 10]);
}

// ---------------------------------------------------------------- host ------
extern "C" void kernel_launch(void* const* d_in, const int* in_sizes, int n_in,
                              void* d_out, int out_size, void* d_ws, size_t ws_size,
                              hipStream_t stream) {
  const float* rgb = (const float*)d_in[0];
  const float* dep = (const float*)d_in[1];
  const float* lid = (const float*)d_in[2];
  const float* pw[3] = {(const float*)d_in[3], (const float*)d_in[5], (const float*)d_in[7]};
  const float* pb[3] = {(const float*)d_in[4], (const float*)d_in[6], (const float*)d_in[8]};
  const float* qw = (const float*)d_in[9];  const float* qb = (const float*)d_in[10];
  const float* kw = (const float*)d_in[11]; const float* kb = (const float*)d_in[12];
  const float* vw = (const float*)d_in[13]; const float* vb = (const float*)d_in[14];
  const float* ow = (const float*)d_in[15]; const float* obv = (const float*)d_in[16];
  const float* sew1 = (const float*)d_in[17]; const float* seb1 = (const float*)d_in[18];
  const float* sew2 = (const float*)d_in[19]; const float* seb2 = (const float*)d_in[20];
  const float* gw = (const float*)d_in[21];   const float* gb = (const float*)d_in[22];
  const float* fw = (const float*)d_in[23]; const float* fbias = (const float*)d_in[24];

  // Pipelined (O-conv merged into next QKV dispatch) needs S = 43 MB
  // (total ~115.5 MB); fall back to the 35-MB sequential layout otherwise.
  // ws_size is constant across calls -> deterministic branch, graph-safe.
  const bool pipe = ws_size >= (116ull << 20);

  char* wp = (char*)d_ws;
  auto carve = [&](size_t bytes) -> char* {
    char* r = wp; wp += (bytes + 255) & ~(size_t)255; return r;
  };
  float* cross = (float*)carve(12L * M1 * 4);    // f32, persists
  short* feat  = (short*)carve(12L * M1 * 2);    // bf16 feats; dead after attn -> fwb
  char*  S     = carve((pipe ? 43L : 35L) * MB);
  float* metrics = (float*)carve(3L * 4096 * 4);
  float* pooled  = (float*)carve(12L * 1024 * 4);
  float* gvec    = (float*)carve(12L * 1024 * 4);

  // S phase 1 (dead after projections):
  short* rgbT = (short*)S;
  short* depT = (short*)(S + 4L * MB);
  short* lidT = (short*)(S + 6L * MB);
  short* pwb[3] = {(short*)(S + 8L * MB), (short*)(S + 9L * MB), (short*)(S + 9728L * 1024)};
  // S phase 2:
  short* Qi  = (short*)S;                       // 8 MB [4][1024 c][1024 d]
  short* Ki  = (short*)(S + 8L * MB);           // 8 MB
  short* Vi  = (short*)(S + 16L * MB);          // 8 MB [4][1024 d][1024 c]
  short* OAi = (short*)(S + 24L * MB);          // 8 MB
  short *wqb, *wkb, *wvb, *wo0, *wo1, *P;
  if (pipe) {
    wqb = (short*)(S + 32L * MB); wkb = (short*)(S + 34L * MB);
    wvb = (short*)(S + 36L * MB); wo0 = (short*)(S + 38L * MB);
    wo1 = (short*)(S + 40L * MB); P   = (short*)(S + 42L * MB);
  } else {
    wqb = (short*)(S + 24L * MB); wkb = (short*)(S + 26L * MB);   // share OA slot
    wvb = (short*)(S + 28L * MB); wo0 = (short*)(S + 32L * MB);
    wo1 = wo0;                    P   = (short*)(S + 34L * MB);
  }
  // S phase 3:
  short* fused = (short*)S;                     // 24 MB
  short* fwb   = feat;                          // 18 MB (feat slot)

  auto G = [&](dim3 grid, GemmP g) { gemm_kernel<<<grid, dim3(256), 0, stream>>>(g); };

  // 1) transpose+convert raw inputs
  trans_k<<<dim3(32, 16, 4), dim3(32, 8), 0, stream>>>(rgb, (bf16*)rgbT, 512, 1024);
  trans_k<<<dim3(32, 8, 4),  dim3(32, 8), 0, stream>>>(dep, (bf16*)depT, 256, 1024);
  trans_k<<<dim3(32, 2, 4),  dim3(32, 8), 0, stream>>>(lid, (bf16*)lidT, 64, 1024);

  // 2) proj weights -> bf16, merged proj GEMM (z=12)
  {
    Cvt4 c{};
    c.s[0] = pw[0]; c.d[0] = (bf16*)pwb[0]; c.n[0] = 1024L * 512;
    c.s[1] = pw[1]; c.d[1] = (bf16*)pwb[1]; c.n[1] = 1024L * 256;
    c.s[2] = pw[2]; c.d[2] = (bf16*)pwb[2]; c.n[2] = 1024L * 64;
    c.s[3] = pw[2]; c.d[3] = (bf16*)pwb[2]; c.n[3] = 0;
    cvt4_k<<<dim3(512, 4), dim3(256), 0, stream>>>(c);

    QkvP q{};
    const int Ks[3] = {512, 256, 64};
    const short* Bts[3] = {rgbT, depT, lidT};
    for (int m = 0; m < 3; m++) {
      q.W[m] = pwb[m]; q.F[m] = Bts[m]; q.C[m] = cross + (long)m * 4 * M1;
      q.bias[m] = pb[m]; q.fl[m] = 1 | 2; q.Kd[m] = Ks[m]; q.ld[m] = Ks[m];
    }
    qkv_kernel<<<dim3(8, 8, 12), dim3(256), 0, stream>>>(q);
  }

  // 3) l2norm + feat + metrics
  norm_k<<<dim3(12288), dim3(256), 0, stream>>>(cross, (bf16*)feat, metrics);

  // 4) attention blocks
  {
    const int qm[6] = {0, 0, 1, 1, 2, 2};
    const int km[6] = {1, 2, 0, 2, 0, 1};
    for (int i = 0; i < 6; i++) {
      short* woCur = (pipe && (i & 1)) ? wo1 : wo0;
      Cvt4 c{};
      c.s[0] = qw + (long)i * M1; c.d[0] = (bf16*)wqb; c.n[0] = M1;
      c.s[1] = kw + (long)i * M1; c.d[1] = (bf16*)wkb; c.n[1] = M1;
      c.s[2] = vw + (long)i * M1; c.d[2] = (bf16*)wvb; c.n[2] = M1;
      c.s[3] = ow + (long)i * M1; c.d[3] = (bf16*)woCur; c.n[3] = M1;
      cvt4_k<<<dim3(1024, 4), dim3(256), 0, stream>>>(c);

      QkvP q{};
      q.W[0] = wqb; q.F[0] = feat + (long)qm[i] * 4 * M1; q.C[0] = Qi;
      q.bias[0] = qb + i * 1024; q.fl[0] = 0;
      q.W[1] = wkb; q.F[1] = feat + (long)km[i] * 4 * M1; q.C[1] = Ki;
      q.bias[1] = kb + i * 1024; q.fl[1] = 0;
      q.W[2] = wvb; q.F[2] = feat + (long)km[i] * 4 * M1; q.C[2] = Vi;
      q.bias[2] = vb + i * 1024; q.fl[2] = 1;
      for (int w = 0; w < 3; w++) { q.Kd[w] = 1024; q.ld[w] = 1024; }
      if (pipe && i > 0) {
        // slot 3 = O-conv of block i-1: cross[qm[i-1]] += Wo[i-1] @ OA
        q.W[3] = (i & 1) ? wo0 : wo1;            // weight converted at i-1
        q.F[3] = OAi; q.C[3] = cross + (long)qm[i - 1] * 4 * M1;
        q.bias[3] = obv + (i - 1) * 1024; q.fl[3] = 1 | 2 | 4;
        q.Kd[3] = 1024; q.ld[3] = 1024;
        qkv_kernel<<<dim3(8, 8, 16), dim3(256), 0, stream>>>(q);
      } else {
        qkv_kernel<<<dim3(8, 8, 12), dim3(256), 0, stream>>>(q);
      }

      attn_sm_k<<<dim3(32), dim3(256), 0, stream>>>(Qi, Ki, (bf16*)P);

      GemmP pv{}; pv.A = P; pv.B = Vi; pv.C = OAi;
      pv.sA1 = 131072; pv.sA2 = 16384; pv.sB1 = M1; pv.sB2 = 128;
      pv.sC1 = M1; pv.sC2 = 128;
      pv.M = 128; pv.N = 1024; pv.K = 128; pv.lda = 128; pv.ldb = 1024; pv.ldc = 1024;
      pv.Z2 = 8; pv.flags = 1;
      G(dim3(8, 1, 32), pv);

      if (!pipe) {
        GemmP o{}; o.A = wo0; o.B = OAi;
        o.C = cross + (long)qm[i] * 4 * M1; o.bias = obv + i * 1024;
        o.sB1 = M1; o.sC1 = M1;
        o.M = 1024; o.N = 1024; o.K = 1024; o.lda = 1024; o.ldb = 1024; o.ldc = 1024;
        o.Z2 = 1; o.flags = 1 | 2 | 4;
        G(dim3(8, 8, 4), o);
      }
    }
    if (pipe) {  // trailing O-conv for i=5 (weight in wo1)
      GemmP o{}; o.A = wo1; o.B = OAi;
      o.C = cross + (long)qm[5] * 4 * M1; o.bias = obv + 5 * 1024;
      o.sB1 = M1; o.sC1 = M1;
      o.M = 1024; o.N = 1024; o.K = 1024; o.lda = 1024; o.ldb = 1024; o.ldc = 1024;
      o.Z2 = 1; o.flags = 1 | 2 | 4;
      G(dim3(8, 8, 4), o);
    }
  }

  // 5) SE
  zero_k<<<dim3(48), dim3(256), 0, stream>>>(pooled, 12 * 1024);
  pool_k<<<dim3(192), dim3(256), 0, stream>>>(cross, pooled);
  se_k<<<dim3(12), dim3(256), 0, stream>>>(pooled, sew1, seb1, sew2, seb2, gvec);

  // 6) gates + fused
  gatefuse_k<<<dim3(4096), dim3(256), 0, stream>>>(cross, gvec, metrics, gw, gb, (bf16*)fused);

  // 7) fusion conv -> d_out f32; m on blockIdx.x (XCD A-strip, flag 32)
  {
    cvt_k<<<dim3(9216), dim3(256), 0, stream>>>(fw, (bf16*)fwb, 9L * M1);
    GemmP g{}; g.A = fwb; g.B = fused; g.C = d_out; g.bias = fbias;
    g.sB1 = (long)1024 * 3072; g.sC1 = (long)3072 * 1024;
    g.M = 3072; g.N = 1024; g.K = 3072; g.lda = 3072; g.ldb = 3072; g.ldc = 1024;
    g.Z2 = 1; g.flags = 2 | 32;
    G(dim3(24, 8, 4), g);
  }
  (void)in_sizes; (void)n_in; (void)out_size;
}

// Round 7
// 1010.486 us; speedup vs baseline: 1.6867x; 1.1401x over previous
//
#include <hip/hip_runtime.h>
#include <hip/hip_bf16.h>

typedef __attribute__((ext_vector_type(8))) short short8;
typedef __attribute__((ext_vector_type(4))) short short4v;
typedef __attribute__((ext_vector_type(4))) float floatx4;
typedef __hip_bfloat16 bf16;

#define M1 1048576L  // 1024*1024
#define MB (1024L * 1024L)

__device__ __forceinline__ void async16(const short* g, short* l) {
  __builtin_amdgcn_global_load_lds((const __attribute__((address_space(1))) void*)g,
                                   (__attribute__((address_space(3))) void*)l, 16, 0, 0);
}

// ------------------------------------------------------- shared GEMM core ---
// 128x128 tile, bf16 MFMA 16x16x32, B transposed ([N][ldb], K-contiguous).
// XOR-swizzled LDS (r6: conflicts 9.4M -> 0). r7: all address math hoisted out
// of the K-loop (r6 PMC: VALUBusy 52% vs MfmaUtil 27% -> VALU-issue-bound).
__device__ __forceinline__ void gemm_loop(const short* A, const short* B, int K,
    int lda, int ldb, short* sA, short* sB, int m0, int n0, floatx4 (&acc)[4][4]) {
  const int tid = threadIdx.x, wave = tid >> 6, lane = tid & 63;
  const int lane15 = lane & 15, quad = lane >> 4;
  const int mW = (wave & 1) * 64, nW = (wave >> 1) * 64;
  const int row4 = lane >> 2;
  const int kcol = ((lane & 3) ^ ((row4 >> 1) & 3)) * 8;  // swizzled fetch quad
  const int psw = (lane15 >> 1) & 3;                       // read-side swizzle
  // hoisted per-lane pointers (advance by 32 shorts per K-step)
  const short* aP0 = A + (long)(m0 + wave * 32 + row4) * lda + kcol;
  const short* aP1 = aP0 + (long)16 * lda;
  const short* bP0 = B + (long)(n0 + wave * 32 + row4) * ldb + kcol;
  const short* bP1 = bP0 + (long)16 * ldb;
  short* sAw = sA + wave * 1024;
  short* sBw = sB + wave * 1024;
  const short* rA = sA + (mW + lane15) * 32 + (quad ^ psw) * 8;
  const short* rB = sB + (nW + lane15) * 32 + (quad ^ psw) * 8;
#pragma unroll
  for (int i = 0; i < 4; i++)
#pragma unroll
    for (int j = 0; j < 4; j++) { floatx4 zz = {0.f, 0.f, 0.f, 0.f}; acc[i][j] = zz; }
  for (int k0 = 0; k0 < K; k0 += 32) {
    __syncthreads();
    async16(aP0, sAw); async16(aP1, sAw + 512);
    async16(bP0, sBw); async16(bP1, sBw + 512);
    aP0 += 32; aP1 += 32; bP0 += 32; bP1 += 32;
    __syncthreads();
    short8 af[4], bfr[4];
#pragma unroll
    for (int mt = 0; mt < 4; mt++) af[mt] = *(const short8*)(rA + mt * 512);
#pragma unroll
    for (int nt = 0; nt < 4; nt++) bfr[nt] = *(const short8*)(rB + nt * 512);
#pragma unroll
    for (int mt = 0; mt < 4; mt++)
#pragma unroll
      for (int nt = 0; nt < 4; nt++)
        acc[mt][nt] = __builtin_amdgcn_mfma_f32_16x16x32_bf16(af[mt], bfr[nt], acc[mt][nt], 0, 0, 0);
  }
}

// flags: 1=C^T  2=f32  4=RMW accumulate (f32 C^T)  32=grid xy swapped
__device__ __forceinline__ void gemm_epi(void* C, const float* bias, long cOff,
    int ldc, int fl, int m0, int n0, floatx4 (&acc)[4][4]) {
  const int lane = threadIdx.x & 63, wave = threadIdx.x >> 6;
  const int lane15 = lane & 15, quad = lane >> 4;
  const int mW = (wave & 1) * 64, nW = (wave >> 1) * 64;
#pragma unroll
  for (int mt = 0; mt < 4; mt++)
#pragma unroll
    for (int nt = 0; nt < 4; nt++) {
      const int mg = m0 + mW + mt * 16 + quad * 4;
      const int ng = n0 + nW + nt * 16 + lane15;
      floatx4 v = acc[mt][nt];
      if (bias) {
        v.x += bias[mg + 0]; v.y += bias[mg + 1];
        v.z += bias[mg + 2]; v.w += bias[mg + 3];
      }
      if (fl & 1) {  // C^T: [N][ldc]
        const long o = cOff + (long)ng * ldc + mg;
        if (fl & 2) {
          float* cp = (float*)C + o;
          if (fl & 4) { v.x += cp[0]; v.y += cp[1]; v.z += cp[2]; v.w += cp[3]; }
          cp[0] = v.x; cp[1] = v.y; cp[2] = v.z; cp[3] = v.w;
        } else {
          bf16* cp = (bf16*)C + o;
          cp[0] = __float2bfloat16(v.x); cp[1] = __float2bfloat16(v.y);
          cp[2] = __float2bfloat16(v.z); cp[3] = __float2bfloat16(v.w);
        }
      } else {       // plain C: [M][ldc]
        const long o = cOff + (long)mg * ldc + ng;
        if (fl & 2) {
          float* cp = (float*)C + o;
          cp[0] = v.x; cp[ldc] = v.y; cp[2L * ldc] = v.z; cp[3L * ldc] = v.w;
        } else {
          bf16* cp = (bf16*)C + o;
          cp[0] = __float2bfloat16(v.x); cp[ldc] = __float2bfloat16(v.y);
          cp[2L * ldc] = __float2bfloat16(v.z); cp[3L * ldc] = __float2bfloat16(v.w);
        }
      }
    }
}

// ------------------------------------------------- generic strided-z GEMM ---
struct GemmP {
  const short* A; const short* B; void* C; const float* bias;
  long sA1, sA2, sB1, sB2, sC1, sC2, sb1, sb2;
  int M, N, K, lda, ldb, ldc, Z2, flags;
};

__global__ __launch_bounds__(256) void gemm_kernel(GemmP p) {
  __shared__ __align__(16) short sA[4096];
  __shared__ __align__(16) short sB[4096];
  const int z = blockIdx.z, z1 = z / p.Z2, z2 = z % p.Z2;
  const short* A = p.A + z1 * p.sA1 + z2 * p.sA2;
  const short* B = p.B + z1 * p.sB1 + z2 * p.sB2;
  const long cOff = z1 * p.sC1 + z2 * p.sC2;
  const float* bias = p.bias;
  if (bias) bias += z1 * p.sb1 + z2 * p.sb2;
  int m0, n0;
  if (p.flags & 32) { m0 = blockIdx.x * 128; n0 = blockIdx.y * 128; }
  else              { m0 = blockIdx.y * 128; n0 = blockIdx.x * 128; }
  floatx4 acc[4][4];
  gemm_loop(A, B, p.K, p.lda, p.ldb, sA, sB, m0, n0, acc);
  gemm_epi(p.C, bias, cOff, p.ldc, p.flags, m0, n0, acc);
}

// -------------------------------- 4-way batched GEMM (proj / QKV [+O]) ------
struct QkvP {
  const short* W[4]; const short* F[4]; void* C[4]; const float* bias[4];
  int fl[4], Kd[4], ld[4];
};

__global__ __launch_bounds__(256) void qkv_kernel(QkvP q) {
  __shared__ __align__(16) short sA[4096];
  __shared__ __align__(16) short sB[4096];
  const int z = blockIdx.z, w = z >> 2, b = z & 3;
  const int K = q.Kd[w], ld = q.ld[w];
  const short* A = q.W[w];
  const short* B = q.F[w] + (long)b * 1024 * K;
  floatx4 acc[4][4];
  gemm_loop(A, B, K, ld, ld, sA, sB, blockIdx.y * 128, blockIdx.x * 128, acc);
  gemm_epi(q.C[w], q.bias[w], (long)b * M1, 1024, q.fl[w], blockIdx.y * 128, blockIdx.x * 128, acc);
}

// ------------------- fused scores + softmax, 32-row blocks (4x occupancy) ---
// grid (32, 4): x = (b,h), y = 32-row strip. Softmax is row-local so strips
// are independent. 128 blocks vs r6's 32 -> 4x CU coverage.
__global__ __launch_bounds__(256) void attn_sm_k(const short* Q, const short* Kt, bf16* P) {
  __shared__ __align__(16) short sA[1024];
  __shared__ __align__(16) short sB[4096];
  __shared__ short S16[32 * 132];
  const int z = blockIdx.x, b = z >> 3, h = z & 7;
  const int r0 = blockIdx.y * 32;
  const int tid = threadIdx.x, wave = tid >> 6, lane = tid & 63;
  const int lane15 = lane & 15, quad = lane >> 4;
  const int row4 = lane >> 2;
  const int kcol = ((lane & 3) ^ ((row4 >> 1) & 3)) * 8;
  const int psw = (lane15 >> 1) & 3;
  const short* Ab = Q + (long)b * M1 + (long)h * 131072;
  const short* Bb = Kt + (long)b * M1 + (long)h * 131072;
  const short* aP = Ab + (long)(r0 + (wave & 1) * 16 + row4) * 1024 + kcol;  // waves 0,1
  const short* bP0 = Bb + (long)(wave * 32 + row4) * 1024 + kcol;
  const short* bP1 = bP0 + (long)16 * 1024;
  short* sBw = sB + wave * 1024;
  const short* rA = sA + lane15 * 32 + (quad ^ psw) * 8;
  const short* rB = sB + (wave * 32 + lane15) * 32 + (quad ^ psw) * 8;
  floatx4 acc[2][2];
#pragma unroll
  for (int i = 0; i < 2; i++)
#pragma unroll
    for (int j = 0; j < 2; j++) { floatx4 zz = {0.f, 0.f, 0.f, 0.f}; acc[i][j] = zz; }
  for (int k0 = 0; k0 < 1024; k0 += 32) {
    __syncthreads();
    if (wave < 2) async16(aP, sA + wave * 512);
    async16(bP0, sBw); async16(bP1, sBw + 512);
    aP += 32; bP0 += 32; bP1 += 32;
    __syncthreads();
    short8 af[2], bfr[2];
    af[0] = *(const short8*)(rA);
    af[1] = *(const short8*)(rA + 512);
    bfr[0] = *(const short8*)(rB);
    bfr[1] = *(const short8*)(rB + 512);
#pragma unroll
    for (int mt = 0; mt < 2; mt++)
#pragma unroll
      for (int nt = 0; nt < 2; nt++)
        acc[mt][nt] = __builtin_amdgcn_mfma_f32_16x16x32_bf16(af[mt], bfr[nt], acc[mt][nt], 0, 0, 0);
  }
  const float sc = 0.08838834764831845f;   // 128^-0.5
#pragma unroll
  for (int mt = 0; mt < 2; mt++)
#pragma unroll
    for (int nt = 0; nt < 2; nt++) {
      const int mg = mt * 16 + quad * 4, ng = wave * 32 + nt * 16 + lane15;
      floatx4 v = acc[mt][nt];
      *(bf16*)&S16[(mg + 0) * 132 + ng] = __float2bfloat16(v.x * sc);
      *(bf16*)&S16[(mg + 1) * 132 + ng] = __float2bfloat16(v.y * sc);
      *(bf16*)&S16[(mg + 2) * 132 + ng] = __float2bfloat16(v.z * sc);
      *(bf16*)&S16[(mg + 3) * 132 + ng] = __float2bfloat16(v.w * sc);
    }
  __syncthreads();
  bf16* Pb = P + (long)z * 16384 + (long)r0 * 128;
#pragma unroll
  for (int j = 0; j < 8; j++) {
    const int r = wave * 8 + j;
    float a = __bfloat162float(*(bf16*)&S16[r * 132 + lane]);
    float c = __bfloat162float(*(bf16*)&S16[r * 132 + lane + 64]);
    float m = fmaxf(a, c);
    for (int off = 32; off; off >>= 1) m = fmaxf(m, __shfl_xor(m, off));
    float e0 = expf(a - m), e1 = expf(c - m), s = e0 + e1;
    for (int off = 32; off; off >>= 1) s += __shfl_xor(s, off);
    const float inv = 1.0f / s;
    Pb[r * 128 + lane] = __float2bfloat16(e0 * inv);
    Pb[r * 128 + lane + 64] = __float2bfloat16(e1 * inv);
  }
}

// -------------------------------------------------------- f32 -> bf16 -------
__global__ void cvt_k(const float* src, bf16* dst, long n) {
  long i = ((long)blockIdx.x * 256 + threadIdx.x) * 4;
  if (i + 3 < n) {
    float4 v = *(const float4*)(src + i);
    bf16 t[4] = {__float2bfloat16(v.x), __float2bfloat16(v.y),
                 __float2bfloat16(v.z), __float2bfloat16(v.w)};
    *(short4v*)(dst + i) = *(short4v*)t;
  }
}

struct Cvt4 { const float* s[4]; bf16* d[4]; long n[4]; };
__global__ void cvt4_k(Cvt4 c) {
  const int seg = blockIdx.y;
  long i = ((long)blockIdx.x * 256 + threadIdx.x) * 4;
  if (i + 3 < c.n[seg]) {
    float4 v = *(const float4*)(c.s[seg] + i);
    bf16 t[4] = {__float2bfloat16(v.x), __float2bfloat16(v.y),
                 __float2bfloat16(v.z), __float2bfloat16(v.w)};
    *(short4v*)(c.d[seg] + i) = *(short4v*)t;
  }
}

// ------------------------------------------------------------ transpose -----
__global__ void trans_k(const float* in, bf16* out, int C, int D) {
  __shared__ float tile[32][33];
  const int d0 = blockIdx.x * 32, c0 = blockIdx.y * 32, b = blockIdx.z;
  const float* ib = in + (long)b * C * D;
  bf16* ob = out + (long)b * C * D;
  for (int i = threadIdx.y; i < 32; i += 8)
    tile[i][threadIdx.x] = ib[(long)(c0 + i) * D + d0 + threadIdx.x];
  __syncthreads();
  for (int i = threadIdx.y; i < 32; i += 8)
    ob[(long)(d0 + i) * C + c0 + threadIdx.x] = __float2bfloat16(tile[threadIdx.x][i]);
}

// ------------------------------------------------------ l2norm + metrics ----
__global__ __launch_bounds__(256) void norm_k(float* cross, bf16* feat, float* metrics) {
  const int blk = blockIdx.x;     // mod*4096 + pix
  const int mod = blk >> 12;
  float* base = cross + (long)blk * 1024;
  bf16* fb = feat + (long)blk * 1024;
  const int t = threadIdx.x;
  float v[4]; float ssq = 0.f;
#pragma unroll
  for (int j = 0; j < 4; j++) { v[j] = base[t + j * 256]; ssq += v[j] * v[j]; }
  __shared__ float r1[256], r2[256], r3[256];
  __shared__ float sinv;
  r1[t] = ssq; __syncthreads();
  for (int s = 128; s > 0; s >>= 1) { if (t < s) r1[t] += r1[t + s]; __syncthreads(); }
  if (t == 0) sinv = 1.0f / fmaxf(sqrtf(r1[0]), 1e-12f);
  __syncthreads();
  const float invn = sinv;
  float s1 = 0.f, s2 = 0.f, zc = 0.f;
#pragma unroll
  for (int j = 0; j < 4; j++) {
    float x = v[j] * invn; v[j] = x;
    s1 += x; s2 += x * x; if (x == 0.0f) zc += 1.0f;
  }
  r1[t] = s1; r2[t] = s2; r3[t] = zc; __syncthreads();
  for (int s = 128; s > 0; s >>= 1) {
    if (t < s) { r1[t] += r1[t + s]; r2[t] += r2[t + s]; r3[t] += r3[t + s]; }
    __syncthreads();
  }
  if (t == 0) {
    float m = (mod == 0) ? (r2[0] - r1[0] * r1[0] * (1.0f / 1024.f)) * (1.0f / 1023.f)
                         : r3[0] * (1.0f / 1024.f);
    metrics[blk] = m;
  }
#pragma unroll
  for (int j = 0; j < 4; j++) { base[t + j * 256] = v[j]; fb[t + j * 256] = __float2bfloat16(v[j]); }
}

// ----------------------------------------------------------------- SE -------
__global__ void zero_k(float* p, int n) {
  int i = blockIdx.x * 256 + threadIdx.x;
  if (i < n) p[i] = 0.f;
}

__global__ void pool_k(const float* cross, float* pooled) {
  const int blk = blockIdx.x;          // mb*16 + seg, mb = mod*4+b
  const int seg = blk & 15, mb = blk >> 4;
  const float* base = cross + (long)mb * M1 + (long)seg * 64 * 1024;
  float* pout = pooled + (long)mb * 1024;
  for (int c = threadIdx.x; c < 1024; c += 256) {
    float s = 0.f;
    for (int d = 0; d < 64; d++) s += base[(long)d * 1024 + c];
    atomicAdd(&pout[c], s * (1.0f / 1024.0f));
  }
}

__global__ void se_k(const float* pooled, const float* w1, const float* b1,
                     const float* w2, const float* b2, float* gvec) {
  const int mb = blockIdx.x, mod = mb >> 2, t = threadIdx.x;
  __shared__ float ps[1024]; __shared__ float hs[64];
  const float* p = pooled + (long)mb * 1024;
  for (int c = t; c < 1024; c += 256) ps[c] = p[c];
  __syncthreads();
  if (t < 64) {
    const float* wr = w1 + (long)(mod * 64 + t) * 1024;
    float s = 0.f;
    for (int c = 0; c < 1024; c++) s += wr[c] * ps[c];
    s += b1[mod * 64 + t];
    hs[t] = fmaxf(s, 0.f);
  }
  __syncthreads();
  for (int o = t; o < 1024; o += 256) {
    const float* wr = w2 + (long)(mod * 1024 + o) * 64;
    float s = 0.f;
    for (int j = 0; j < 64; j++) s += wr[j] * hs[j];
    s += b2[mod * 1024 + o];
    gvec[(long)mb * 1024 + o] = 1.0f / (1.0f + expf(-s));
  }
}

// ------------------------------------------------------- gates + fused ------
__global__ __launch_bounds__(256) void gatefuse_k(const float* cross, const float* gvec,
    const float* metrics, const float* gw, const float* gb, bf16* fused) {
  const int pix = blockIdx.x;          // b*1024 + d
  const int b = pix >> 10, t = threadIdx.x;
  __shared__ float refbuf[3072];
  __shared__ float red[3][256];
  __shared__ float gsh[3];
  float p0 = 0.f, p1 = 0.f, p2 = 0.f;
  for (int mod = 0; mod < 3; mod++) {
    const float* cb = cross + ((long)mod * 4096 + pix) * 1024;
    const float* gv = gvec + (long)(mod * 4 + b) * 1024;
    for (int c = t; c < 1024; c += 256) {
      float val = cb[c] * gv[c];
      refbuf[mod * 1024 + c] = val;
      p0 += gw[0 * 3075 + mod * 1024 + c] * val;
      p1 += gw[1 * 3075 + mod * 1024 + c] * val;
      p2 += gw[2 * 3075 + mod * 1024 + c] * val;
    }
  }
  red[0][t] = p0; red[1][t] = p1; red[2][t] = p2; __syncthreads();
  for (int s = 128; s > 0; s >>= 1) {
    if (t < s) { red[0][t] += red[0][t + s]; red[1][t] += red[1][t + s]; red[2][t] += red[2][t + s]; }
    __syncthreads();
  }
  if (t == 0) {
    const float var = metrics[pix], spd = metrics[4096 + pix], spl = metrics[8192 + pix];
    for (int j = 0; j < 3; j++) {
      float s = red[j][0] + gw[j * 3075 + 3072] * var + gw[j * 3075 + 3073] * spd
              + gw[j * 3075 + 3074] * spl + gb[j];
      gsh[j] = 1.0f / (1.0f + expf(-s));
    }
  }
  __syncthreads();
  bf16* fb = fused + (long)pix * 3072;
  for (int i = t; i < 3072; i += 256) fb[i] = __float2bfloat16(refbuf[i] * gsh[i >> 10]);
}

// ---------------------------------------------------------------- host ------
extern "C" void kernel_launch(void* const* d_in, const int* in_sizes, int n_in,
                              void* d_out, int out_size, void* d_ws, size_t ws_size,
                              hipStream_t stream) {
  const float* rgb = (const float*)d_in[0];
  const float* dep = (const float*)d_in[1];
  const float* lid = (const float*)d_in[2];
  const float* pw[3] = {(const float*)d_in[3], (const float*)d_in[5], (const float*)d_in[7]};
  const float* pb[3] = {(const float*)d_in[4], (const float*)d_in[6], (const float*)d_in[8]};
  const float* qw = (const float*)d_in[9];  const float* qb = (const float*)d_in[10];
  const float* kw = (const float*)d_in[11]; const float* kb = (const float*)d_in[12];
  const float* vw = (const float*)d_in[13]; const float* vb = (const float*)d_in[14];
  const float* ow = (const float*)d_in[15]; const float* obv = (const float*)d_in[16];
  const float* sew1 = (const float*)d_in[17]; const float* seb1 = (const float*)d_in[18];
  const float* sew2 = (const float*)d_in[19]; const float* seb2 = (const float*)d_in[20];
  const float* gw = (const float*)d_in[21];   const float* gb = (const float*)d_in[22];
  const float* fw = (const float*)d_in[23]; const float* fbias = (const float*)d_in[24];

  // Mode ladder (ws_size constant across calls -> deterministic, graph-safe):
  //   wall (>=170 MB): all attention weights converted upfront (one dispatch)
  //   pipe (>=116 MB): O-conv of block i-1 merged into QKV dispatch of i
  //   else: round-5 sequential layout (proven at ~107 MB)
  const bool wall = ws_size >= (170ull << 20);
  const bool pipe = wall || ws_size >= (116ull << 20);

  char* wp = (char*)d_ws;
  auto carve = [&](size_t bytes) -> char* {
    char* r = wp; wp += (bytes + 255) & ~(size_t)255; return r;
  };
  float* cross = (float*)carve(12L * M1 * 4);    // f32, persists
  short* feat  = (short*)carve(12L * M1 * 2);    // bf16 feats; dead after attn -> fwb
  char*  S     = carve((!wall && pipe ? 43L : 35L) * MB);
  float* metrics = (float*)carve(3L * 4096 * 4);
  float* pooled  = (float*)carve(12L * 1024 * 4);
  float* gvec    = (float*)carve(12L * 1024 * 4);
  short* W = wall ? (short*)carve(24L * M1 * 2) : (short*)0;  // 48 MB weight pool

  // S phase 1 (dead after projections):
  short* rgbT = (short*)S;
  short* depT = (short*)(S + 4L * MB);
  short* lidT = (short*)(S + 6L * MB);
  short* pwb[3] = {(short*)(S + 8L * MB), (short*)(S + 9L * MB), (short*)(S + 9728L * 1024)};
  // S phase 2:
  short* Qi  = (short*)S;                       // 8 MB [4][1024 c][1024 d]
  short* Ki  = (short*)(S + 8L * MB);           // 8 MB
  short* Vi  = (short*)(S + 16L * MB);          // 8 MB [4][1024 d][1024 c]
  short* OAi = (short*)(S + 24L * MB);          // 8 MB
  short *wqb, *wkb, *wvb, *wo0, *wo1, *P;
  if (wall) {
    wqb = wkb = wvb = wo0 = wo1 = (short*)0;    // unused
    P = (short*)(S + 32L * MB);
  } else if (pipe) {
    wqb = (short*)(S + 32L * MB); wkb = (short*)(S + 34L * MB);
    wvb = (short*)(S + 36L * MB); wo0 = (short*)(S + 38L * MB);
    wo1 = (short*)(S + 40L * MB); P   = (short*)(S + 42L * MB);
  } else {
    wqb = (short*)(S + 24L * MB); wkb = (short*)(S + 26L * MB);   // share OA slot
    wvb = (short*)(S + 28L * MB); wo0 = (short*)(S + 32L * MB);
    wo1 = wo0;                    P   = (short*)(S + 34L * MB);
  }
  // S phase 3:
  short* fused = (short*)S;                     // 24 MB
  short* fwb   = feat;                          // 18 MB (feat slot)

  auto G = [&](dim3 grid, GemmP g) { gemm_kernel<<<grid, dim3(256), 0, stream>>>(g); };

  // 0) wall: convert ALL attention weights in one dispatch
  if (wall) {
    Cvt4 c{};
    c.s[0] = qw; c.d[0] = (bf16*)(W + 0L * M1);  c.n[0] = 6L * M1;
    c.s[1] = kw; c.d[1] = (bf16*)(W + 6L * M1);  c.n[1] = 6L * M1;
    c.s[2] = vw; c.d[2] = (bf16*)(W + 12L * M1); c.n[2] = 6L * M1;
    c.s[3] = ow; c.d[3] = (bf16*)(W + 18L * M1); c.n[3] = 6L * M1;
    cvt4_k<<<dim3(6144, 4), dim3(256), 0, stream>>>(c);
  }

  // 1) transpose+convert raw inputs
  trans_k<<<dim3(32, 16, 4), dim3(32, 8), 0, stream>>>(rgb, (bf16*)rgbT, 512, 1024);
  trans_k<<<dim3(32, 8, 4),  dim3(32, 8), 0, stream>>>(dep, (bf16*)depT, 256, 1024);
  trans_k<<<dim3(32, 2, 4),  dim3(32, 8), 0, stream>>>(lid, (bf16*)lidT, 64, 1024);

  // 2) proj weights -> bf16, merged proj GEMM (z=12)
  {
    Cvt4 c{};
    c.s[0] = pw[0]; c.d[0] = (bf16*)pwb[0]; c.n[0] = 1024L * 512;
    c.s[1] = pw[1]; c.d[1] = (bf16*)pwb[1]; c.n[1] = 1024L * 256;
    c.s[2] = pw[2]; c.d[2] = (bf16*)pwb[2]; c.n[2] = 1024L * 64;
    c.s[3] = pw[2]; c.d[3] = (bf16*)pwb[2]; c.n[3] = 0;
    cvt4_k<<<dim3(512, 4), dim3(256), 0, stream>>>(c);

    QkvP q{};
    const int Ks[3] = {512, 256, 64};
    const short* Bts[3] = {rgbT, depT, lidT};
    for (int m = 0; m < 3; m++) {
      q.W[m] = pwb[m]; q.F[m] = Bts[m]; q.C[m] = cross + (long)m * 4 * M1;
      q.bias[m] = pb[m]; q.fl[m] = 1 | 2; q.Kd[m] = Ks[m]; q.ld[m] = Ks[m];
    }
    qkv_kernel<<<dim3(8, 8, 12), dim3(256), 0, stream>>>(q);
  }

  // 3) l2norm + feat + metrics
  norm_k<<<dim3(12288), dim3(256), 0, stream>>>(cross, (bf16*)feat, metrics);

  // 4) attention blocks
  {
    const int qm[6] = {0, 0, 1, 1, 2, 2};
    const int km[6] = {1, 2, 0, 2, 0, 1};
    for (int i = 0; i < 6; i++) {
      const short *wq_i, *wk_i, *wv_i, *woPrev;
      if (wall) {
        wq_i = W + (long)i * M1; wk_i = W + (long)(6 + i) * M1;
        wv_i = W + (long)(12 + i) * M1; woPrev = W + (long)(18 + i - 1) * M1;
      } else {
        short* woCur = (pipe && (i & 1)) ? wo1 : wo0;
        Cvt4 c{};
        c.s[0] = qw + (long)i * M1; c.d[0] = (bf16*)wqb; c.n[0] = M1;
        c.s[1] = kw + (long)i * M1; c.d[1] = (bf16*)wkb; c.n[1] = M1;
        c.s[2] = vw + (long)i * M1; c.d[2] = (bf16*)wvb; c.n[2] = M1;
        c.s[3] = ow + (long)i * M1; c.d[3] = (bf16*)woCur; c.n[3] = M1;
        cvt4_k<<<dim3(1024, 4), dim3(256), 0, stream>>>(c);
        wq_i = wqb; wk_i = wkb; wv_i = wvb;
        woPrev = (i & 1) ? wo0 : wo1;
      }

      QkvP q{};
      q.W[0] = wq_i; q.F[0] = feat + (long)qm[i] * 4 * M1; q.C[0] = Qi;
      q.bias[0] = qb + i * 1024; q.fl[0] = 0;
      q.W[1] = wk_i; q.F[1] = feat + (long)km[i] * 4 * M1; q.C[1] = Ki;
      q.bias[1] = kb + i * 1024; q.fl[1] = 0;
      q.W[2] = wv_i; q.F[2] = feat + (long)km[i] * 4 * M1; q.C[2] = Vi;
      q.bias[2] = vb + i * 1024; q.fl[2] = 1;
      for (int w = 0; w < 3; w++) { q.Kd[w] = 1024; q.ld[w] = 1024; }
      if (pipe && i > 0) {
        // slot 3 = O-conv of block i-1: cross[qm[i-1]] += Wo[i-1] @ OA
        q.W[3] = woPrev;
        q.F[3] = OAi; q.C[3] = cross + (long)qm[i - 1] * 4 * M1;
        q.bias[3] = obv + (i - 1) * 1024; q.fl[3] = 1 | 2 | 4;
        q.Kd[3] = 1024; q.ld[3] = 1024;
        qkv_kernel<<<dim3(8, 8, 16), dim3(256), 0, stream>>>(q);
      } else {
        qkv_kernel<<<dim3(8, 8, 12), dim3(256), 0, stream>>>(q);
      }

      attn_sm_k<<<dim3(32, 4), dim3(256), 0, stream>>>(Qi, Ki, (bf16*)P);

      GemmP pv{}; pv.A = P; pv.B = Vi; pv.C = OAi;
      pv.sA1 = 131072; pv.sA2 = 16384; pv.sB1 = M1; pv.sB2 = 128;
      pv.sC1 = M1; pv.sC2 = 128;
      pv.M = 128; pv.N = 1024; pv.K = 128; pv.lda = 128; pv.ldb = 1024; pv.ldc = 1024;
      pv.Z2 = 8; pv.flags = 1;
      G(dim3(8, 1, 32), pv);

      if (!pipe) {
        GemmP o{}; o.A = wo0; o.B = OAi;
        o.C = cross + (long)qm[i] * 4 * M1; o.bias = obv + i * 1024;
        o.sB1 = M1; o.sC1 = M1;
        o.M = 1024; o.N = 1024; o.K = 1024; o.lda = 1024; o.ldb = 1024; o.ldc = 1024;
        o.Z2 = 1; o.flags = 1 | 2 | 4;
        G(dim3(8, 8, 4), o);
      }
    }
    if (pipe) {  // trailing O-conv for i=5
      GemmP o{}; o.A = wall ? (W + 23L * M1) : wo1; o.B = OAi;
      o.C = cross + (long)qm[5] * 4 * M1; o.bias = obv + 5 * 1024;
      o.sB1 = M1; o.sC1 = M1;
      o.M = 1024; o.N = 1024; o.K = 1024; o.lda = 1024; o.ldb = 1024; o.ldc = 1024;
      o.Z2 = 1; o.flags = 1 | 2 | 4;
      G(dim3(8, 8, 4), o);
    }
  }

  // 5) SE
  zero_k<<<dim3(48), dim3(256), 0, stream>>>(pooled, 12 * 1024);
  pool_k<<<dim3(192), dim3(256), 0, stream>>>(cross, pooled);
  se_k<<<dim3(12), dim3(256), 0, stream>>>(pooled, sew1, seb1, sew2, seb2, gvec);

  // 6) gates + fused
  gatefuse_k<<<dim3(4096), dim3(256), 0, stream>>>(cross, gvec, metrics, gw, gb, (bf16*)fused);

  // 7) fusion conv -> d_out f32; m on blockIdx.x (XCD A-strip, flag 32)
  {
    cvt_k<<<dim3(9216), dim3(256), 0, stream>>>(fw, (bf16*)fwb, 9L * M1);
    GemmP g{}; g.A = fwb; g.B = fused; g.C = d_out; g.bias = fbias;
    g.sB1 = (long)1024 * 3072; g.sC1 = (long)3072 * 1024;
    g.M = 3072; g.N = 1024; g.K = 3072; g.lda = 3072; g.ldb = 3072; g.ldc = 1024;
    g.Z2 = 1; g.flags = 2 | 32;
    G(dim3(24, 8, 4), g);
  }
  (void)in_sizes; (void)n_in; (void)out_size;
}